// Round 1
// baseline (222.896 us; speedup 1.0000x reference)
//
#include <hip/hip_runtime.h>
#include <hip/hip_bf16.h>
#include <stdint.h>

typedef __attribute__((ext_vector_type(8))) short bf16x8;
typedef __attribute__((ext_vector_type(4))) float f32x4;
typedef __attribute__((ext_vector_type(4))) unsigned int u32x4;

#define NB 256
#define CC 128

static __device__ __forceinline__ unsigned int cvt_pk_bf16(float lo, float hi) {
  unsigned int r;
  asm("v_cvt_pk_bf16_f32 %0, %1, %2" : "=v"(r) : "v"(lo), "v"(hi));
  return r;
}

// ---- k0a: Wc^T (bf16) = (W_edge @ W3)^T ; bc = b_edge@W3 + b_pre ----
__global__ void k_prep_w(const float* __restrict__ W_edge, const float* __restrict__ b_edge,
                         const float* __restrict__ W_pre, const float* __restrict__ b_pre,
                         uint16_t* __restrict__ wct, float* __restrict__ bc) {
  const int k = blockIdx.x;   // 0..127
  const int c = threadIdx.x;  // 0..127
  float acc = 0.f;
  for (int q = 0; q < CC; ++q)
    acc += W_edge[k * CC + q] * W_pre[(2 * CC + q) * CC + c];
  unsigned u = __builtin_bit_cast(unsigned, acc);
  unsigned r = (u + 0x7FFFu + ((u >> 16) & 1u)) >> 16;   // RNE to bf16
  wct[c * CC + k] = (uint16_t)r;                         // store transposed
  if (k == 0) {
    float a2 = b_pre[c];
    for (int q = 0; q < CC; ++q) a2 += b_edge[q] * W_pre[(2 * CC + q) * CC + c];
    bc[c] = a2;
  }
}

// ---- k0b: At = x@W1 + bc ; Bv = x@W2 ----
__global__ void k_prep_nodes(const float* __restrict__ x, const float* __restrict__ W_pre,
                             const float* __restrict__ bc, float* __restrict__ At,
                             float* __restrict__ Bv) {
  const int m = blockIdx.x;    // b*N + n
  const int c = threadIdx.x;   // 0..127
  __shared__ float xs[CC];
  xs[c] = x[m * CC + c];
  __syncthreads();
  float a = 0.f, v = 0.f;
  for (int k = 0; k < CC; ++k) {
    float xv = xs[k];
    a += xv * W_pre[k * CC + c];
    v += xv * W_pre[(CC + k) * CC + c];
  }
  At[m * CC + c] = a + bc[c];
  Bv[m * CC + c] = v;
}

// ---- k1: fused edge GEMM + PNA reduction over j ----
__global__ __launch_bounds__(256, 2) void k_edge(
    const float* __restrict__ edge, const uint16_t* __restrict__ wct,
    const float* __restrict__ At, const float* __restrict__ Bv,
    float* __restrict__ agg) {
  const int blk = blockIdx.x;          // b*256 + i
  const int b   = blk >> 8;
  const int tid = threadIdx.x;
  const int lane = tid & 63;
  const int wv  = tid >> 6;            // 0..3 waves
  const int g   = lane >> 4;           // 0..3
  const int lr  = lane & 15;
  const int cb  = wv * 32;             // 32 output channels per wave (2 tiles)

  // Resident B fragments: Wc^T rows = output channels, 8 contiguous k per lane
  bf16x8 bfr[2][4];
#pragma unroll
  for (int t = 0; t < 2; ++t) {
    const uint16_t* p = wct + (cb + t * 16 + lr) * CC + g * 8;
#pragma unroll
    for (int ks = 0; ks < 4; ++ks)
      bfr[t][ks] = *(const bf16x8*)(p + ks * 32);
  }

  const float* ep0 = edge + (size_t)blk * (NB * CC) + lr * CC + g * 8;
  const float* bvp = Bv + (size_t)b * (NB * CC);

  float sum0 = 0.f, sum1 = 0.f, ssq0 = 0.f, ssq1 = 0.f;
  float mn0 = 1e30f, mn1 = 1e30f, mx0 = -1e30f, mx1 = -1e30f;

  for (int jc = 0; jc < 16; ++jc) {
    const float* ep = ep0 + jc * 16 * CC;
    f32x4 lo[4], hi[4];
#pragma unroll
    for (int ks = 0; ks < 4; ++ks) {
      lo[ks] = *(const f32x4*)(ep + ks * 32);
      hi[ks] = *(const f32x4*)(ep + ks * 32 + 4);
    }
    f32x4 acc0 = {0.f, 0.f, 0.f, 0.f}, acc1 = {0.f, 0.f, 0.f, 0.f};
#pragma unroll
    for (int ks = 0; ks < 4; ++ks) {
      u32x4 aw;
      aw.x = cvt_pk_bf16(lo[ks].x, lo[ks].y);
      aw.y = cvt_pk_bf16(lo[ks].z, lo[ks].w);
      aw.z = cvt_pk_bf16(hi[ks].x, hi[ks].y);
      aw.w = cvt_pk_bf16(hi[ks].z, hi[ks].w);
      bf16x8 af = __builtin_bit_cast(bf16x8, aw);
      acc0 = __builtin_amdgcn_mfma_f32_16x16x32_bf16(af, bfr[0][ks], acc0, 0, 0, 0);
      acc1 = __builtin_amdgcn_mfma_f32_16x16x32_bf16(af, bfr[1][ks], acc1, 0, 0, 0);
    }
    // epilogue: j = jc*16 + g*4 + r ; s = E' + Bv[b,j,c]
    const float* bvr = bvp + (size_t)(jc * 16 + g * 4) * CC;
#pragma unroll
    for (int r = 0; r < 4; ++r) {
      float s0 = acc0[r] + bvr[r * CC + cb + lr];
      float s1 = acc1[r] + bvr[r * CC + cb + 16 + lr];
      sum0 += s0; ssq0 = fmaf(s0, s0, ssq0);
      mn0 = fminf(mn0, s0); mx0 = fmaxf(mx0, s0);
      sum1 += s1; ssq1 = fmaf(s1, s1, ssq1);
      mn1 = fminf(mn1, s1); mx1 = fmaxf(mx1, s1);
    }
  }
  // reduce across the 4 row-groups (lane bits 4,5)
#pragma unroll
  for (int m = 16; m <= 32; m <<= 1) {
    sum0 += __shfl_xor(sum0, m); ssq0 += __shfl_xor(ssq0, m);
    mn0 = fminf(mn0, __shfl_xor(mn0, m)); mx0 = fmaxf(mx0, __shfl_xor(mx0, m));
    sum1 += __shfl_xor(sum1, m); ssq1 += __shfl_xor(ssq1, m);
    mn1 = fminf(mn1, __shfl_xor(mn1, m)); mx1 = fmaxf(mx1, __shfl_xor(mx1, m));
  }
  if (g == 0) {
#pragma unroll
    for (int t = 0; t < 2; ++t) {
      const int col = cb + t * 16 + lr;
      const float s   = t ? sum1 : sum0;
      const float q   = t ? ssq1 : ssq0;
      const float mnv = t ? mn1 : mn0;
      const float mxv = t ? mx1 : mx0;
      const float tt = At[blk * CC + col];
      const float mean = s * (1.f / NB);
      const float var = q * (1.f / NB) - mean * mean;
      const float sd = sqrtf(fmaxf(var, 0.f) + 1e-5f);
      float* ap = agg + (size_t)blk * (4 * CC) + col;
      ap[0]      = tt + mean;
      ap[CC]     = tt + mnv;
      ap[2 * CC] = tt + mxv;
      ap[3 * CC] = sd;     // std is invariant to the j-constant term
    }
  }
}

// ---- k2: out = [x,agg]@W_post + b_post ; out@W_lin + b_lin ; per-block GN partials ----
__global__ __launch_bounds__(256) void k_post(
    const float* __restrict__ x, const float* __restrict__ agg,
    const float* __restrict__ W_post, const float* __restrict__ b_post,
    const float* __restrict__ W_lin, const float* __restrict__ b_lin,
    float* __restrict__ outl, float* __restrict__ psum, float* __restrict__ psq) {
  __shared__ float hx[16][5 * CC];
  __shared__ float o1[16][CC];
  __shared__ float pl[4][CC];
  const int blk = blockIdx.x;    // 128 blocks x 16 rows
  const int t = threadIdx.x;
  const int row0 = blk * 16;

  for (int idx = t; idx < 16 * 5 * CC; idx += 256) {
    int r = idx / (5 * CC), col = idx - r * (5 * CC);
    hx[r][col] = (col < CC) ? x[(size_t)(row0 + r) * CC + col]
                            : agg[(size_t)(row0 + r) * (4 * CC) + (col - CC)];
  }
  __syncthreads();

  const int c = t & (CC - 1);
  const int rh = t >> 7;  // 0/1
  float acc[8];
#pragma unroll
  for (int i = 0; i < 8; ++i) acc[i] = b_post[c];
  for (int k = 0; k < 5 * CC; k += 4) {
    float w0 = W_post[(k + 0) * CC + c];
    float w1 = W_post[(k + 1) * CC + c];
    float w2 = W_post[(k + 2) * CC + c];
    float w3 = W_post[(k + 3) * CC + c];
#pragma unroll
    for (int i = 0; i < 8; ++i) {
      const f32x4 h4 = *(const f32x4*)&hx[2 * i + rh][k];
      acc[i] += h4.x * w0 + h4.y * w1 + h4.z * w2 + h4.w * w3;
    }
  }
#pragma unroll
  for (int i = 0; i < 8; ++i) o1[2 * i + rh][c] = acc[i];
  __syncthreads();

  float a2[8];
#pragma unroll
  for (int i = 0; i < 8; ++i) a2[i] = b_lin[c];
  for (int k = 0; k < CC; k += 4) {
    float w0 = W_lin[(k + 0) * CC + c];
    float w1 = W_lin[(k + 1) * CC + c];
    float w2 = W_lin[(k + 2) * CC + c];
    float w3 = W_lin[(k + 3) * CC + c];
#pragma unroll
    for (int i = 0; i < 8; ++i) {
      const f32x4 h4 = *(const f32x4*)&o1[2 * i + rh][k];
      a2[i] += h4.x * w0 + h4.y * w1 + h4.z * w2 + h4.w * w3;
    }
  }
  float ps = 0.f, pq = 0.f;
#pragma unroll
  for (int i = 0; i < 8; ++i) {
    outl[(size_t)(row0 + 2 * i + rh) * CC + c] = a2[i];
    ps += a2[i]; pq += a2[i] * a2[i];
  }
  pl[rh][c] = ps; pl[2 + rh][c] = pq;
  __syncthreads();
  if (t < CC) {
    psum[blk * CC + t] = pl[0][t] + pl[1][t];
    psq[blk * CC + t]  = pl[2][t] + pl[3][t];
  }
}

// ---- k3: GraphNorm stats over all 2048 nodes ----
__global__ void k_stats(const float* __restrict__ psum, const float* __restrict__ psq,
                        const float* __restrict__ alpha, float* __restrict__ stats) {
  const int c = threadIdx.x;  // 128
  float s = 0.f, q = 0.f;
  for (int i = 0; i < 128; ++i) { s += psum[i * CC + c]; q += psq[i * CC + c]; }
  const float mu = s * (1.f / 2048.f);
  const float ex2 = q * (1.f / 2048.f);
  const float a = alpha[c];
  const float v = ex2 - 2.f * a * mu * mu + a * a * mu * mu;
  stats[c] = mu;
  stats[CC + c] = 1.f / sqrtf(v + 1e-5f);
}

// ---- k4: normalize + relu + residual ----
__global__ void k_apply(const float* __restrict__ outl, const float* __restrict__ x,
                        const float* __restrict__ stats, const float* __restrict__ gw,
                        const float* __restrict__ gb, const float* __restrict__ alpha,
                        float* __restrict__ y) {
  const int idx = blockIdx.x * 256 + threadIdx.x;
  const int c = idx & (CC - 1);
  const float o = outl[idx];
  const float cen = o - alpha[c] * stats[c];
  const float v = gw[c] * cen * stats[CC + c] + gb[c];
  y[idx] = fmaxf(v, 0.f) + x[idx];
}

extern "C" void kernel_launch(void* const* d_in, const int* in_sizes, int n_in,
                              void* d_out, int out_size, void* d_ws, size_t ws_size,
                              hipStream_t stream) {
  const float* x      = (const float*)d_in[0];
  const float* edge   = (const float*)d_in[1];
  const float* W_edge = (const float*)d_in[2];
  const float* b_edge = (const float*)d_in[3];
  const float* W_pre  = (const float*)d_in[4];
  const float* b_pre  = (const float*)d_in[5];
  const float* W_post = (const float*)d_in[6];
  const float* b_post = (const float*)d_in[7];
  const float* W_lin  = (const float*)d_in[8];
  const float* b_lin  = (const float*)d_in[9];
  const float* gw     = (const float*)d_in[10];
  const float* gb     = (const float*)d_in[11];
  const float* alpha  = (const float*)d_in[12];
  float* y = (float*)d_out;

  float* wsf = (float*)d_ws;
  float* bc    = wsf;                // 128
  float* At    = wsf + 128;          // 2048*128
  float* Bv    = wsf + 262272;       // 2048*128
  float* agg   = wsf + 524416;       // 2048*512
  float* outl  = wsf + 1572992;      // 2048*128
  float* psum  = wsf + 1835136;      // 128*128
  float* psq   = wsf + 1851520;      // 128*128
  float* stats = wsf + 1867904;      // 256
  uint16_t* wct = (uint16_t*)(wsf + 1868160);  // 128*128 bf16

  k_prep_w<<<128, 128, 0, stream>>>(W_edge, b_edge, W_pre, b_pre, wct, bc);
  k_prep_nodes<<<2048, 128, 0, stream>>>(x, W_pre, bc, At, Bv);
  k_edge<<<2048, 256, 0, stream>>>(edge, wct, At, Bv, agg);
  k_post<<<128, 256, 0, stream>>>(x, agg, W_post, b_post, W_lin, b_lin, outl, psum, psq);
  k_stats<<<1, 128, 0, stream>>>(psum, psq, alpha, stats);
  k_apply<<<1024, 256, 0, stream>>>(outl, x, stats, gw, gb, alpha, y);
}

// Round 2
// 195.470 us; speedup vs baseline: 1.1403x; 1.1403x over previous
//
#include <hip/hip_runtime.h>
#include <hip/hip_bf16.h>
#include <stdint.h>

typedef __attribute__((ext_vector_type(8))) short bf16x8;
typedef __attribute__((ext_vector_type(4))) float f32x4;
typedef __attribute__((ext_vector_type(4))) unsigned int u32x4;

#define NB 256
#define CC 128

static __device__ __forceinline__ unsigned int cvt_pk_bf16(float lo, float hi) {
  unsigned int r;
  asm("v_cvt_pk_bf16_f32 %0, %1, %2" : "=v"(r) : "v"(lo), "v"(hi));
  return r;
}

// ---- k0a: Wc^T (bf16) = (W_edge @ W3)^T ; bc = b_edge@W3 + b_pre ----
__global__ void k_prep_w(const float* __restrict__ W_edge, const float* __restrict__ b_edge,
                         const float* __restrict__ W_pre, const float* __restrict__ b_pre,
                         uint16_t* __restrict__ wct, float* __restrict__ bc) {
  const int k = blockIdx.x;   // 0..127
  const int c = threadIdx.x;  // 0..127
  float acc = 0.f;
  for (int q = 0; q < CC; ++q)
    acc += W_edge[k * CC + q] * W_pre[(2 * CC + q) * CC + c];
  unsigned u = __builtin_bit_cast(unsigned, acc);
  unsigned r = (u + 0x7FFFu + ((u >> 16) & 1u)) >> 16;   // RNE to bf16
  wct[c * CC + k] = (uint16_t)r;                         // store transposed
  if (k == 0) {
    float a2 = b_pre[c];
    for (int q = 0; q < CC; ++q) a2 += b_edge[q] * W_pre[(2 * CC + q) * CC + c];
    bc[c] = a2;
  }
}

// ---- k0b: At = x@W1 + bc ; Bv = x@W2 ----
__global__ void k_prep_nodes(const float* __restrict__ x, const float* __restrict__ W_pre,
                             const float* __restrict__ bc, float* __restrict__ At,
                             float* __restrict__ Bv) {
  const int m = blockIdx.x;    // b*N + n
  const int c = threadIdx.x;   // 0..127
  __shared__ float xs[CC];
  xs[c] = x[m * CC + c];
  __syncthreads();
  float a = 0.f, v = 0.f;
  for (int k = 0; k < CC; ++k) {
    float xv = xs[k];
    a += xv * W_pre[k * CC + c];
    v += xv * W_pre[(CC + k) * CC + c];
  }
  At[m * CC + c] = a + bc[c];
  Bv[m * CC + c] = v;
}

// ---- k1: fused edge GEMM + PNA reduction over j, 2-deep register pipeline ----
#define LOAD_EDGE(LO, HI, JC) do {                                   \
    const float* ep_ = ep0 + (size_t)(JC) * 16 * CC;                 \
    _Pragma("unroll") for (int ks = 0; ks < 4; ++ks) {               \
      LO[ks] = *(const f32x4*)(ep_ + ks * 32);                       \
      HI[ks] = *(const f32x4*)(ep_ + ks * 32 + 4);                   \
    }                                                                \
  } while (0)

#define LOAD_BV(BV, JC) do {                                         \
    const float* bvr_ = bvp + (size_t)((JC) * 16 + g * 4) * CC;      \
    _Pragma("unroll") for (int r = 0; r < 4; ++r) {                  \
      BV[r]     = bvr_[r * CC + cb + lr];                            \
      BV[4 + r] = bvr_[r * CC + cb + 16 + lr];                       \
    }                                                                \
  } while (0)

#define COMPUTE(LO, HI, BV) do {                                                  \
    f32x4 acc0 = {0.f,0.f,0.f,0.f}, acc1 = {0.f,0.f,0.f,0.f};                     \
    _Pragma("unroll") for (int ks = 0; ks < 4; ++ks) {                            \
      u32x4 aw;                                                                   \
      aw.x = cvt_pk_bf16(LO[ks].x, LO[ks].y);                                     \
      aw.y = cvt_pk_bf16(LO[ks].z, LO[ks].w);                                     \
      aw.z = cvt_pk_bf16(HI[ks].x, HI[ks].y);                                     \
      aw.w = cvt_pk_bf16(HI[ks].z, HI[ks].w);                                     \
      bf16x8 af = __builtin_bit_cast(bf16x8, aw);                                 \
      acc0 = __builtin_amdgcn_mfma_f32_16x16x32_bf16(af, bfr[0][ks], acc0, 0,0,0);\
      acc1 = __builtin_amdgcn_mfma_f32_16x16x32_bf16(af, bfr[1][ks], acc1, 0,0,0);\
    }                                                                             \
    _Pragma("unroll") for (int r = 0; r < 4; ++r) {                               \
      float s0 = acc0[r] + BV[r];                                                 \
      float s1 = acc1[r] + BV[4 + r];                                             \
      sum0 += s0; ssq0 = fmaf(s0, s0, ssq0);                                      \
      mn0 = fminf(mn0, s0); mx0 = fmaxf(mx0, s0);                                 \
      sum1 += s1; ssq1 = fmaf(s1, s1, ssq1);                                      \
      mn1 = fminf(mn1, s1); mx1 = fmaxf(mx1, s1);                                 \
    }                                                                             \
  } while (0)

__global__ __launch_bounds__(256, 2) void k_edge(
    const float* __restrict__ edge, const uint16_t* __restrict__ wct,
    const float* __restrict__ At, const float* __restrict__ Bv,
    float* __restrict__ agg) {
  const int blk = blockIdx.x;          // b*256 + i
  const int b   = blk >> 8;
  const int tid = threadIdx.x;
  const int lane = tid & 63;
  const int wv  = tid >> 6;            // 0..3 waves
  const int g   = lane >> 4;           // 0..3
  const int lr  = lane & 15;
  const int cb  = wv * 32;             // 32 output channels per wave (2 tiles)

  // Resident B fragments: Wc^T rows = output channels, 8 contiguous k per lane
  bf16x8 bfr[2][4];
#pragma unroll
  for (int t = 0; t < 2; ++t) {
    const uint16_t* p = wct + (cb + t * 16 + lr) * CC + g * 8;
#pragma unroll
    for (int ks = 0; ks < 4; ++ks)
      bfr[t][ks] = *(const bf16x8*)(p + ks * 32);
  }

  const float* ep0 = edge + (size_t)blk * (NB * CC) + lr * CC + g * 8;
  const float* bvp = Bv + (size_t)b * (NB * CC);

  float sum0 = 0.f, sum1 = 0.f, ssq0 = 0.f, ssq1 = 0.f;
  float mn0 = 1e30f, mn1 = 1e30f, mx0 = -1e30f, mx1 = -1e30f;

  f32x4 loA[4], hiA[4], loB[4], hiB[4];
  float bvA[8], bvB[8];

  LOAD_BV(bvA, 0);
  LOAD_EDGE(loA, hiA, 0);
  __builtin_amdgcn_sched_barrier(0);

#pragma unroll 1
  for (int jc = 0; jc < 14; jc += 2) {
    LOAD_BV(bvB, jc + 1);
    LOAD_EDGE(loB, hiB, jc + 1);
    __builtin_amdgcn_sched_barrier(0);
    COMPUTE(loA, hiA, bvA);
    LOAD_BV(bvA, jc + 2);
    LOAD_EDGE(loA, hiA, jc + 2);
    __builtin_amdgcn_sched_barrier(0);
    COMPUTE(loB, hiB, bvB);
  }
  // tail: jc = 14, 15
  LOAD_BV(bvB, 15);
  LOAD_EDGE(loB, hiB, 15);
  __builtin_amdgcn_sched_barrier(0);
  COMPUTE(loA, hiA, bvA);
  COMPUTE(loB, hiB, bvB);

  // reduce across the 4 row-groups (lane bits 4,5)
#pragma unroll
  for (int m = 16; m <= 32; m <<= 1) {
    sum0 += __shfl_xor(sum0, m); ssq0 += __shfl_xor(ssq0, m);
    mn0 = fminf(mn0, __shfl_xor(mn0, m)); mx0 = fmaxf(mx0, __shfl_xor(mx0, m));
    sum1 += __shfl_xor(sum1, m); ssq1 += __shfl_xor(ssq1, m);
    mn1 = fminf(mn1, __shfl_xor(mn1, m)); mx1 = fmaxf(mx1, __shfl_xor(mx1, m));
  }
  if (g == 0) {
#pragma unroll
    for (int t = 0; t < 2; ++t) {
      const int col = cb + t * 16 + lr;
      const float s   = t ? sum1 : sum0;
      const float q   = t ? ssq1 : ssq0;
      const float mnv = t ? mn1 : mn0;
      const float mxv = t ? mx1 : mx0;
      const float tt = At[blk * CC + col];
      const float mean = s * (1.f / NB);
      const float var = q * (1.f / NB) - mean * mean;
      const float sd = sqrtf(fmaxf(var, 0.f) + 1e-5f);
      float* ap = agg + (size_t)blk * (4 * CC) + col;
      ap[0]      = tt + mean;
      ap[CC]     = tt + mnv;
      ap[2 * CC] = tt + mxv;
      ap[3 * CC] = sd;     // std is invariant to the j-constant term
    }
  }
}

// ---- k2: out = [x,agg]@W_post + b_post ; out@W_lin + b_lin ; per-block GN partials ----
__global__ __launch_bounds__(256) void k_post(
    const float* __restrict__ x, const float* __restrict__ agg,
    const float* __restrict__ W_post, const float* __restrict__ b_post,
    const float* __restrict__ W_lin, const float* __restrict__ b_lin,
    float* __restrict__ outl, float* __restrict__ psum, float* __restrict__ psq) {
  __shared__ float hx[8][5 * CC];
  __shared__ float o1[8][CC];
  __shared__ float pl[4][CC];
  const int blk = blockIdx.x;    // 256 blocks x 8 rows
  const int t = threadIdx.x;
  const int row0 = blk * 8;

  for (int idx = t; idx < 8 * 5 * CC; idx += 256) {
    int r = idx / (5 * CC), col = idx - r * (5 * CC);
    hx[r][col] = (col < CC) ? x[(size_t)(row0 + r) * CC + col]
                            : agg[(size_t)(row0 + r) * (4 * CC) + (col - CC)];
  }
  __syncthreads();

  const int c = t & (CC - 1);
  const int rh = t >> 7;  // 0/1
  float acc[4];
#pragma unroll
  for (int i = 0; i < 4; ++i) acc[i] = b_post[c];
  for (int k = 0; k < 5 * CC; k += 4) {
    float w0 = W_post[(k + 0) * CC + c];
    float w1 = W_post[(k + 1) * CC + c];
    float w2 = W_post[(k + 2) * CC + c];
    float w3 = W_post[(k + 3) * CC + c];
#pragma unroll
    for (int i = 0; i < 4; ++i) {
      const f32x4 h4 = *(const f32x4*)&hx[2 * i + rh][k];
      acc[i] += h4.x * w0 + h4.y * w1 + h4.z * w2 + h4.w * w3;
    }
  }
#pragma unroll
  for (int i = 0; i < 4; ++i) o1[2 * i + rh][c] = acc[i];
  __syncthreads();

  float a2[4];
#pragma unroll
  for (int i = 0; i < 4; ++i) a2[i] = b_lin[c];
  for (int k = 0; k < CC; k += 4) {
    float w0 = W_lin[(k + 0) * CC + c];
    float w1 = W_lin[(k + 1) * CC + c];
    float w2 = W_lin[(k + 2) * CC + c];
    float w3 = W_lin[(k + 3) * CC + c];
#pragma unroll
    for (int i = 0; i < 4; ++i) {
      const f32x4 h4 = *(const f32x4*)&o1[2 * i + rh][k];
      a2[i] += h4.x * w0 + h4.y * w1 + h4.z * w2 + h4.w * w3;
    }
  }
  float ps = 0.f, pq = 0.f;
#pragma unroll
  for (int i = 0; i < 4; ++i) {
    outl[(size_t)(row0 + 2 * i + rh) * CC + c] = a2[i];
    ps += a2[i]; pq += a2[i] * a2[i];
  }
  pl[rh][c] = ps; pl[2 + rh][c] = pq;
  __syncthreads();
  if (t < CC) {
    psum[blk * CC + t] = pl[0][t] + pl[1][t];
    psq[blk * CC + t]  = pl[2][t] + pl[3][t];
  }
}

// ---- k3: GraphNorm stats over all 2048 nodes ----
__global__ void k_stats(const float* __restrict__ psum, const float* __restrict__ psq,
                        const float* __restrict__ alpha, float* __restrict__ stats) {
  const int c = threadIdx.x;  // 128
  float s = 0.f, q = 0.f;
  for (int i = 0; i < 256; ++i) { s += psum[i * CC + c]; q += psq[i * CC + c]; }
  const float mu = s * (1.f / 2048.f);
  const float ex2 = q * (1.f / 2048.f);
  const float a = alpha[c];
  const float v = ex2 - 2.f * a * mu * mu + a * a * mu * mu;
  stats[c] = mu;
  stats[CC + c] = 1.f / sqrtf(v + 1e-5f);
}

// ---- k4: normalize + relu + residual ----
__global__ void k_apply(const float* __restrict__ outl, const float* __restrict__ x,
                        const float* __restrict__ stats, const float* __restrict__ gw,
                        const float* __restrict__ gb, const float* __restrict__ alpha,
                        float* __restrict__ y) {
  const int idx = blockIdx.x * 256 + threadIdx.x;
  const int c = idx & (CC - 1);
  const float o = outl[idx];
  const float cen = o - alpha[c] * stats[c];
  const float v = gw[c] * cen * stats[CC + c] + gb[c];
  y[idx] = fmaxf(v, 0.f) + x[idx];
}

extern "C" void kernel_launch(void* const* d_in, const int* in_sizes, int n_in,
                              void* d_out, int out_size, void* d_ws, size_t ws_size,
                              hipStream_t stream) {
  const float* x      = (const float*)d_in[0];
  const float* edge   = (const float*)d_in[1];
  const float* W_edge = (const float*)d_in[2];
  const float* b_edge = (const float*)d_in[3];
  const float* W_pre  = (const float*)d_in[4];
  const float* b_pre  = (const float*)d_in[5];
  const float* W_post = (const float*)d_in[6];
  const float* b_post = (const float*)d_in[7];
  const float* W_lin  = (const float*)d_in[8];
  const float* b_lin  = (const float*)d_in[9];
  const float* gw     = (const float*)d_in[10];
  const float* gb     = (const float*)d_in[11];
  const float* alpha  = (const float*)d_in[12];
  float* y = (float*)d_out;

  float* wsf = (float*)d_ws;
  float* bc    = wsf;                // 128
  float* At    = wsf + 128;          // 2048*128
  float* Bv    = wsf + 262272;       // 2048*128
  float* agg   = wsf + 524416;       // 2048*512
  float* outl  = wsf + 1572992;      // 2048*128
  float* psum  = wsf + 1835136;      // 256*128
  float* psq   = wsf + 1867904;      // 256*128
  float* stats = wsf + 1900672;      // 256
  uint16_t* wct = (uint16_t*)(wsf + 1900928);  // 128*128 bf16

  k_prep_w<<<128, 128, 0, stream>>>(W_edge, b_edge, W_pre, b_pre, wct, bc);
  k_prep_nodes<<<2048, 128, 0, stream>>>(x, W_pre, bc, At, Bv);
  k_edge<<<2048, 256, 0, stream>>>(edge, wct, At, Bv, agg);
  k_post<<<256, 256, 0, stream>>>(x, agg, W_post, b_post, W_lin, b_lin, outl, psum, psq);
  k_stats<<<1, 128, 0, stream>>>(psum, psq, alpha, stats);
  k_apply<<<1024, 256, 0, stream>>>(outl, x, stats, gw, gb, alpha, y);
}

// Round 3
// 113.696 us; speedup vs baseline: 1.9605x; 1.7192x over previous
//
#include <hip/hip_runtime.h>
#include <hip/hip_bf16.h>
#include <stdint.h>

typedef __attribute__((ext_vector_type(8))) short bf16x8;
typedef __attribute__((ext_vector_type(4))) float f32x4;
typedef __attribute__((ext_vector_type(4))) unsigned int u32x4;

#define NB 256
#define CC 128

typedef const __attribute__((address_space(1))) void* gvp;
typedef __attribute__((address_space(3))) void* lvp;
#define GLOAD_LDS16(GP, LP) \
  __builtin_amdgcn_global_load_lds((gvp)(uintptr_t)(GP), (lvp)(uintptr_t)(LP), 16, 0, 0)

static __device__ __forceinline__ unsigned int cvt_pk_bf16(float lo, float hi) {
  unsigned int r;
  asm("v_cvt_pk_bf16_f32 %0, %1, %2" : "=v"(r) : "v"(lo), "v"(hi));
  return r;
}
static __device__ __forceinline__ uint16_t f2bf(float f) {
  unsigned u = __builtin_bit_cast(unsigned, f);
  return (uint16_t)((u + 0x7FFFu + ((u >> 16) & 1u)) >> 16);
}

// ---- k0a: wct = (W_edge @ W3)^T bf16 ; w2t = W2^T bf16 ; bc = b_edge@W3 + b_pre ----
__global__ void k_prep_w(const float* __restrict__ W_edge, const float* __restrict__ b_edge,
                         const float* __restrict__ W_pre, const float* __restrict__ b_pre,
                         uint16_t* __restrict__ wct, uint16_t* __restrict__ w2t,
                         float* __restrict__ bc) {
  const int k = blockIdx.x;   // 0..127 (input channel)
  const int c = threadIdx.x;  // 0..127 (output channel)
  float acc = 0.f;
  for (int q = 0; q < CC; ++q)
    acc += W_edge[k * CC + q] * W_pre[(2 * CC + q) * CC + c];
  wct[c * CC + k] = f2bf(acc);                        // store transposed
  w2t[c * CC + k] = f2bf(W_pre[(CC + k) * CC + c]);   // W2 transposed
  if (k == 0) {
    float a2 = b_pre[c];
    for (int q = 0; q < CC; ++q) a2 += b_edge[q] * W_pre[(2 * CC + q) * CC + c];
    bc[c] = a2;
  }
}

// ---- k0b: At = x@W1 + bc ; xbf = bf16(x) ----
__global__ void k_prep_nodes(const float* __restrict__ x, const float* __restrict__ W_pre,
                             const float* __restrict__ bc, float* __restrict__ At,
                             uint16_t* __restrict__ xbf) {
  const int m = blockIdx.x;    // b*N + n
  const int c = threadIdx.x;   // 0..127
  __shared__ float xs[CC];
  xs[c] = x[m * CC + c];
  __syncthreads();
  float a = 0.f;
  for (int k = 0; k < CC; ++k) a += xs[k] * W_pre[k * CC + c];
  At[m * CC + c] = a + bc[c];
  xbf[m * CC + c] = f2bf(xs[c]);
}

// ---- k1: fused concat-GEMM [e|x] @ [Wc;W2] + PNA reduction, LDS async pipeline ----
__global__ __launch_bounds__(256, 3) void k_edge(
    const float* __restrict__ edge, const uint16_t* __restrict__ wct,
    const uint16_t* __restrict__ w2t, const uint16_t* __restrict__ xbf,
    const float* __restrict__ At, float* __restrict__ agg) {
  __shared__ __align__(16) float    ebuf[4][2048];   // 4 x 8 KB (16 j-rows x 128 k fp32)
  __shared__ __align__(16) uint16_t xbuf[4][2048];   // 4 x 4 KB (16 j-rows x 128 k bf16)

  const int blk  = blockIdx.x;         // b*256 + i
  const int b    = blk >> 8;
  const int tid  = threadIdx.x;
  const int lane = tid & 63;
  const int wv   = tid >> 6;           // 0..3
  const int g    = lane >> 4;          // 0..3
  const int lr   = lane & 15;
  const int cb   = wv * 32;            // 32 output channels per wave

  // B fragments: [ctile][kslice]; kslice 0..3 from wct (edge part), 4..7 from w2t (x part)
  bf16x8 bfr[2][8];
#pragma unroll
  for (int t = 0; t < 2; ++t) {
    const uint16_t* p1 = wct + (cb + t * 16 + lr) * CC + g * 8;
    const uint16_t* p2 = w2t + (cb + t * 16 + lr) * CC + g * 8;
#pragma unroll
    for (int ks = 0; ks < 4; ++ks) {
      bfr[t][ks]     = *(const bf16x8*)(p1 + ks * 32);
      bfr[t][4 + ks] = *(const bf16x8*)(p2 + ks * 32);
    }
  }
  // drain bfr loads so the vmcnt FIFO holds ONLY stage ops from here on
  asm volatile("s_waitcnt vmcnt(0)" ::: "memory");

  // staging source offsets (per-lane, swizzle pre-applied to SOURCE; LDS dest linear)
  const uint32_t eL0 = wv * 2048 + lane * 16;
  const uint32_t eL1 = eL0 + 1024;
  const uint32_t eS0 = eL0 ^ (((eL0 >> 9) & 7) << 4);
  const uint32_t eS1 = eL1 ^ (((eL1 >> 9) & 7) << 4);
  const uint32_t xL0 = wv * 1024 + lane * 16;
  const uint32_t xS0 = xL0 ^ (((xL0 >> 8) & 7) << 4);

  const char* egbase = (const char*)(edge + (size_t)blk * (NB * CC));
  const char* xgbase = (const char*)(xbf + (size_t)b * (NB * CC));

  auto STAGE = [&](int t) {
    const char* eg = egbase + (size_t)t * 8192;
    const char* xg = xgbase + (size_t)t * 4096;
    char* el = (char*)&ebuf[t & 3][0];
    char* xl = (char*)&xbuf[t & 3][0];
    GLOAD_LDS16(eg + eS0, el + wv * 2048);
    GLOAD_LDS16(eg + eS1, el + wv * 2048 + 1024);
    GLOAD_LDS16(xg + xS0, xl + wv * 1024);
  };

  float sum0 = 0.f, sum1 = 0.f, ssq0 = 0.f, ssq1 = 0.f;
  float mn0 = 1e30f, mn1 = 1e30f, mx0 = -1e30f, mx1 = -1e30f;
  const int swz = (lr & 7) << 4;

  auto COMPUTE = [&](int t) {
    const char* eb = (const char*)&ebuf[t & 3][0] + lr * 512;
    const char* xb = (const char*)&xbuf[t & 3][0] + lr * 256;
    f32x4 acc0 = {0.f, 0.f, 0.f, 0.f}, acc1 = {0.f, 0.f, 0.f, 0.f};
#pragma unroll
    for (int ks = 0; ks < 4; ++ks) {
      const int off = g * 32 + ks * 128;
      f32x4 lo = *(const f32x4*)(eb + (off ^ swz));
      f32x4 hi = *(const f32x4*)(eb + ((off + 16) ^ swz));
      u32x4 aw;
      aw.x = cvt_pk_bf16(lo.x, lo.y);
      aw.y = cvt_pk_bf16(lo.z, lo.w);
      aw.z = cvt_pk_bf16(hi.x, hi.y);
      aw.w = cvt_pk_bf16(hi.z, hi.w);
      bf16x8 af = __builtin_bit_cast(bf16x8, aw);
      acc0 = __builtin_amdgcn_mfma_f32_16x16x32_bf16(af, bfr[0][ks], acc0, 0, 0, 0);
      acc1 = __builtin_amdgcn_mfma_f32_16x16x32_bf16(af, bfr[1][ks], acc1, 0, 0, 0);
    }
#pragma unroll
    for (int k2 = 0; k2 < 4; ++k2) {
      bf16x8 xa = *(const bf16x8*)(xb + ((g * 16 + k2 * 64) ^ swz));
      acc0 = __builtin_amdgcn_mfma_f32_16x16x32_bf16(xa, bfr[0][4 + k2], acc0, 0, 0, 0);
      acc1 = __builtin_amdgcn_mfma_f32_16x16x32_bf16(xa, bfr[1][4 + k2], acc1, 0, 0, 0);
    }
#pragma unroll
    for (int r = 0; r < 4; ++r) {
      float s0 = acc0[r], s1 = acc1[r];
      sum0 += s0; ssq0 = fmaf(s0, s0, ssq0);
      mn0 = fminf(mn0, s0); mx0 = fmaxf(mx0, s0);
      sum1 += s1; ssq1 = fmaf(s1, s1, ssq1);
      mn1 = fminf(mn1, s1); mx1 = fmaxf(mx1, s1);
    }
  };

  STAGE(0); STAGE(1); STAGE(2);

#pragma unroll 1
  for (int t = 0; t < 13; ++t) {
    asm volatile("s_waitcnt vmcnt(6)" ::: "memory");   // tile t landed (3 ops/tile, 2 ahead)
    __builtin_amdgcn_s_barrier();
    __builtin_amdgcn_sched_barrier(0);
    STAGE(t + 3);
    __builtin_amdgcn_sched_barrier(0);
    COMPUTE(t);
  }
  asm volatile("s_waitcnt vmcnt(6)" ::: "memory");
  __builtin_amdgcn_s_barrier();
  __builtin_amdgcn_sched_barrier(0);
  COMPUTE(13);
  asm volatile("s_waitcnt vmcnt(3)" ::: "memory");
  __builtin_amdgcn_s_barrier();
  __builtin_amdgcn_sched_barrier(0);
  COMPUTE(14);
  asm volatile("s_waitcnt vmcnt(0)" ::: "memory");
  __builtin_amdgcn_s_barrier();
  __builtin_amdgcn_sched_barrier(0);
  COMPUTE(15);

  // reduce across the 4 row-groups (lane bits 4,5)
#pragma unroll
  for (int m = 16; m <= 32; m <<= 1) {
    sum0 += __shfl_xor(sum0, m); ssq0 += __shfl_xor(ssq0, m);
    mn0 = fminf(mn0, __shfl_xor(mn0, m)); mx0 = fmaxf(mx0, __shfl_xor(mx0, m));
    sum1 += __shfl_xor(sum1, m); ssq1 += __shfl_xor(ssq1, m);
    mn1 = fminf(mn1, __shfl_xor(mn1, m)); mx1 = fmaxf(mx1, __shfl_xor(mx1, m));
  }
  if (g == 0) {
#pragma unroll
    for (int t = 0; t < 2; ++t) {
      const int col = cb + t * 16 + lr;
      const float s   = t ? sum1 : sum0;
      const float q   = t ? ssq1 : ssq0;
      const float mnv = t ? mn1 : mn0;
      const float mxv = t ? mx1 : mx0;
      const float tt = At[blk * CC + col];
      const float mean = s * (1.f / NB);
      const float var = q * (1.f / NB) - mean * mean;
      const float sd = sqrtf(fmaxf(var, 0.f) + 1e-5f);
      float* ap = agg + (size_t)blk * (4 * CC) + col;
      ap[0]      = tt + mean;
      ap[CC]     = tt + mnv;
      ap[2 * CC] = tt + mxv;
      ap[3 * CC] = sd;     // std is invariant to the j-constant term
    }
  }
}

// ---- k2: out = [x,agg]@W_post + b_post ; out@W_lin + b_lin ; per-block GN partials ----
__global__ __launch_bounds__(256) void k_post(
    const float* __restrict__ x, const float* __restrict__ agg,
    const float* __restrict__ W_post, const float* __restrict__ b_post,
    const float* __restrict__ W_lin, const float* __restrict__ b_lin,
    float* __restrict__ outl, float* __restrict__ psum, float* __restrict__ psq) {
  __shared__ float hx[8][5 * CC];
  __shared__ float o1[8][CC];
  __shared__ float pl[4][CC];
  const int blk = blockIdx.x;    // 256 blocks x 8 rows
  const int t = threadIdx.x;
  const int row0 = blk * 8;

  for (int idx = t; idx < 8 * 5 * CC; idx += 256) {
    int r = idx / (5 * CC), col = idx - r * (5 * CC);
    hx[r][col] = (col < CC) ? x[(size_t)(row0 + r) * CC + col]
                            : agg[(size_t)(row0 + r) * (4 * CC) + (col - CC)];
  }
  __syncthreads();

  const int c = t & (CC - 1);
  const int rh = t >> 7;  // 0/1
  float acc[4];
#pragma unroll
  for (int i = 0; i < 4; ++i) acc[i] = b_post[c];
  for (int k = 0; k < 5 * CC; k += 4) {
    float w0 = W_post[(k + 0) * CC + c];
    float w1 = W_post[(k + 1) * CC + c];
    float w2 = W_post[(k + 2) * CC + c];
    float w3 = W_post[(k + 3) * CC + c];
#pragma unroll
    for (int i = 0; i < 4; ++i) {
      const f32x4 h4 = *(const f32x4*)&hx[2 * i + rh][k];
      acc[i] += h4.x * w0 + h4.y * w1 + h4.z * w2 + h4.w * w3;
    }
  }
#pragma unroll
  for (int i = 0; i < 4; ++i) o1[2 * i + rh][c] = acc[i];
  __syncthreads();

  float a2[4];
#pragma unroll
  for (int i = 0; i < 4; ++i) a2[i] = b_lin[c];
  for (int k = 0; k < CC; k += 4) {
    float w0 = W_lin[(k + 0) * CC + c];
    float w1 = W_lin[(k + 1) * CC + c];
    float w2 = W_lin[(k + 2) * CC + c];
    float w3 = W_lin[(k + 3) * CC + c];
#pragma unroll
    for (int i = 0; i < 4; ++i) {
      const f32x4 h4 = *(const f32x4*)&o1[2 * i + rh][k];
      a2[i] += h4.x * w0 + h4.y * w1 + h4.z * w2 + h4.w * w3;
    }
  }
  float ps = 0.f, pq = 0.f;
#pragma unroll
  for (int i = 0; i < 4; ++i) {
    outl[(size_t)(row0 + 2 * i + rh) * CC + c] = a2[i];
    ps += a2[i]; pq += a2[i] * a2[i];
  }
  pl[rh][c] = ps; pl[2 + rh][c] = pq;
  __syncthreads();
  if (t < CC) {
    psum[blk * CC + t] = pl[0][t] + pl[1][t];
    psq[blk * CC + t]  = pl[2][t] + pl[3][t];
  }
}

// ---- k3: GraphNorm stats over all 2048 nodes ----
__global__ void k_stats(const float* __restrict__ psum, const float* __restrict__ psq,
                        const float* __restrict__ alpha, float* __restrict__ stats) {
  const int c = threadIdx.x;  // 128
  float s = 0.f, q = 0.f;
  for (int i = 0; i < 256; ++i) { s += psum[i * CC + c]; q += psq[i * CC + c]; }
  const float mu = s * (1.f / 2048.f);
  const float ex2 = q * (1.f / 2048.f);
  const float a = alpha[c];
  const float v = ex2 - 2.f * a * mu * mu + a * a * mu * mu;
  stats[c] = mu;
  stats[CC + c] = 1.f / sqrtf(v + 1e-5f);
}

// ---- k4: normalize + relu + residual ----
__global__ void k_apply(const float* __restrict__ outl, const float* __restrict__ x,
                        const float* __restrict__ stats, const float* __restrict__ gw,
                        const float* __restrict__ gb, const float* __restrict__ alpha,
                        float* __restrict__ y) {
  const int idx = blockIdx.x * 256 + threadIdx.x;
  const int c = idx & (CC - 1);
  const float o = outl[idx];
  const float cen = o - alpha[c] * stats[c];
  const float v = gw[c] * cen * stats[CC + c] + gb[c];
  y[idx] = fmaxf(v, 0.f) + x[idx];
}

extern "C" void kernel_launch(void* const* d_in, const int* in_sizes, int n_in,
                              void* d_out, int out_size, void* d_ws, size_t ws_size,
                              hipStream_t stream) {
  const float* x      = (const float*)d_in[0];
  const float* edge   = (const float*)d_in[1];
  const float* W_edge = (const float*)d_in[2];
  const float* b_edge = (const float*)d_in[3];
  const float* W_pre  = (const float*)d_in[4];
  const float* b_pre  = (const float*)d_in[5];
  const float* W_post = (const float*)d_in[6];
  const float* b_post = (const float*)d_in[7];
  const float* W_lin  = (const float*)d_in[8];
  const float* b_lin  = (const float*)d_in[9];
  const float* gw     = (const float*)d_in[10];
  const float* gb     = (const float*)d_in[11];
  const float* alpha  = (const float*)d_in[12];
  float* y = (float*)d_out;

  float* wsf = (float*)d_ws;
  float* bc    = wsf;                 // 128
  float* At    = wsf + 128;           // 2048*128
  float* agg   = wsf + 262272;        // 2048*512
  float* outl  = wsf + 1310848;       // 2048*128
  float* psum  = wsf + 1572992;       // 256*128
  float* psq   = wsf + 1605760;       // 256*128
  float* stats = wsf + 1638528;       // 256
  uint16_t* wct = (uint16_t*)(wsf + 1638784);  // 128*128 bf16
  uint16_t* w2t = (uint16_t*)(wsf + 1646976);  // 128*128 bf16
  uint16_t* xbf = (uint16_t*)(wsf + 1655168);  // 2048*128 bf16

  k_prep_w<<<128, 128, 0, stream>>>(W_edge, b_edge, W_pre, b_pre, wct, w2t, bc);
  k_prep_nodes<<<2048, 128, 0, stream>>>(x, W_pre, bc, At, xbf);
  k_edge<<<2048, 256, 0, stream>>>(edge, wct, w2t, xbf, At, agg);
  k_post<<<256, 256, 0, stream>>>(x, agg, W_post, b_post, W_lin, b_lin, outl, psum, psq);
  k_stats<<<1, 128, 0, stream>>>(psum, psq, alpha, stats);
  k_apply<<<1024, 256, 0, stream>>>(outl, x, stats, gw, gb, alpha, y);
}

// Round 4
// 112.976 us; speedup vs baseline: 1.9729x; 1.0064x over previous
//
#include <hip/hip_runtime.h>
#include <hip/hip_bf16.h>
#include <stdint.h>

typedef __attribute__((ext_vector_type(8))) short bf16x8;
typedef __attribute__((ext_vector_type(4))) float f32x4;
typedef __attribute__((ext_vector_type(4))) unsigned int u32x4;

#define NB 256
#define CC 128

typedef const __attribute__((address_space(1))) void* gvp;
typedef __attribute__((address_space(3))) void* lvp;
#define GLOAD_LDS16(GP, LP) \
  __builtin_amdgcn_global_load_lds((gvp)(uintptr_t)(GP), (lvp)(uintptr_t)(LP), 16, 0, 0)

static __device__ __forceinline__ unsigned int cvt_pk_bf16(float lo, float hi) {
  unsigned int r;
  asm("v_cvt_pk_bf16_f32 %0, %1, %2" : "=v"(r) : "v"(lo), "v"(hi));
  return r;
}
static __device__ __forceinline__ uint16_t f2bf(float f) {
  unsigned u = __builtin_bit_cast(unsigned, f);
  return (uint16_t)((u + 0x7FFFu + ((u >> 16) & 1u)) >> 16);
}

// ---- k_prep (fused): blocks 0..127 -> weight prep; blocks 128.. -> node prep ----
__global__ void k_prep(const float* __restrict__ W_edge, const float* __restrict__ b_edge,
                       const float* __restrict__ W_pre, const float* __restrict__ b_pre,
                       const float* __restrict__ x,
                       uint16_t* __restrict__ wct, uint16_t* __restrict__ w2t,
                       float* __restrict__ bc2, float* __restrict__ At,
                       uint16_t* __restrict__ xbf) {
  const int c = threadIdx.x;  // 0..127
  if (blockIdx.x < 128) {
    const int k = blockIdx.x;   // input channel
    float acc = 0.f;
    for (int q = 0; q < CC; ++q)
      acc += W_edge[k * CC + q] * W_pre[(2 * CC + q) * CC + c];
    wct[c * CC + k] = f2bf(acc);                        // (W_edge@W3)^T, bf16
    w2t[c * CC + k] = f2bf(W_pre[(CC + k) * CC + c]);   // W2^T, bf16
    if (k == 0) {
      float a2 = b_pre[c];
      for (int q = 0; q < CC; ++q) a2 += b_edge[q] * W_pre[(2 * CC + q) * CC + c];
      bc2[c] = a2;
    }
  } else {
    const int m = blockIdx.x - 128;   // node row
    __shared__ float xs[CC];
    xs[c] = x[m * CC + c];
    __syncthreads();
    float a = 0.f;
#pragma unroll 8
    for (int k = 0; k < CC; ++k) a += xs[k] * W_pre[k * CC + c];
    At[m * CC + c] = a;               // x@W1 (bias folded in k_edge epilogue)
    xbf[m * CC + c] = f2bf(xs[c]);
  }
}

// ---- k1: fused concat-GEMM [e|x] @ [Wc;W2] + PNA reduction, LDS async pipeline ----
__global__ __launch_bounds__(256, 3) void k_edge(
    const float* __restrict__ edge, const uint16_t* __restrict__ wct,
    const uint16_t* __restrict__ w2t, const uint16_t* __restrict__ xbf,
    const float* __restrict__ At, const float* __restrict__ bc2,
    float* __restrict__ agg) {
  __shared__ __align__(16) float    ebuf[4][2048];   // 4 x 8 KB (16 j-rows x 128 k fp32)
  __shared__ __align__(16) uint16_t xbuf[4][2048];   // 4 x 4 KB (16 j-rows x 128 k bf16)

  const int blk  = blockIdx.x;         // b*256 + i
  const int b    = blk >> 8;
  const int tid  = threadIdx.x;
  const int lane = tid & 63;
  const int wv   = tid >> 6;           // 0..3
  const int g    = lane >> 4;          // 0..3
  const int lr   = lane & 15;
  const int cb   = wv * 32;            // 32 output channels per wave

  // B fragments: [ctile][kslice]; kslice 0..3 from wct (edge part), 4..7 from w2t (x part)
  bf16x8 bfr[2][8];
#pragma unroll
  for (int t = 0; t < 2; ++t) {
    const uint16_t* p1 = wct + (cb + t * 16 + lr) * CC + g * 8;
    const uint16_t* p2 = w2t + (cb + t * 16 + lr) * CC + g * 8;
#pragma unroll
    for (int ks = 0; ks < 4; ++ks) {
      bfr[t][ks]     = *(const bf16x8*)(p1 + ks * 32);
      bfr[t][4 + ks] = *(const bf16x8*)(p2 + ks * 32);
    }
  }
  // drain bfr loads so the vmcnt FIFO holds ONLY stage ops from here on
  asm volatile("s_waitcnt vmcnt(0)" ::: "memory");

  // staging source offsets (per-lane, swizzle pre-applied to SOURCE; LDS dest linear)
  const uint32_t eL0 = wv * 2048 + lane * 16;
  const uint32_t eL1 = eL0 + 1024;
  const uint32_t eS0 = eL0 ^ (((eL0 >> 9) & 7) << 4);
  const uint32_t eS1 = eL1 ^ (((eL1 >> 9) & 7) << 4);
  const uint32_t xL0 = wv * 1024 + lane * 16;
  const uint32_t xS0 = xL0 ^ (((xL0 >> 8) & 7) << 4);

  const char* egbase = (const char*)(edge + (size_t)blk * (NB * CC));
  const char* xgbase = (const char*)(xbf + (size_t)b * (NB * CC));

  auto STAGE = [&](int t) {
    const char* eg = egbase + (size_t)t * 8192;
    const char* xg = xgbase + (size_t)t * 4096;
    char* el = (char*)&ebuf[t & 3][0];
    char* xl = (char*)&xbuf[t & 3][0];
    GLOAD_LDS16(eg + eS0, el + wv * 2048);
    GLOAD_LDS16(eg + eS1, el + wv * 2048 + 1024);
    GLOAD_LDS16(xg + xS0, xl + wv * 1024);
  };

  float sum0 = 0.f, sum1 = 0.f, ssq0 = 0.f, ssq1 = 0.f;
  float mn0 = 1e30f, mn1 = 1e30f, mx0 = -1e30f, mx1 = -1e30f;
  const int swz = (lr & 7) << 4;

  auto COMPUTE = [&](int t) {
    const char* eb = (const char*)&ebuf[t & 3][0] + lr * 512;
    const char* xb = (const char*)&xbuf[t & 3][0] + lr * 256;
    f32x4 acc0 = {0.f, 0.f, 0.f, 0.f}, acc1 = {0.f, 0.f, 0.f, 0.f};
#pragma unroll
    for (int ks = 0; ks < 4; ++ks) {
      const int off = g * 32 + ks * 128;
      f32x4 lo = *(const f32x4*)(eb + (off ^ swz));
      f32x4 hi = *(const f32x4*)(eb + ((off + 16) ^ swz));
      u32x4 aw;
      aw.x = cvt_pk_bf16(lo.x, lo.y);
      aw.y = cvt_pk_bf16(lo.z, lo.w);
      aw.z = cvt_pk_bf16(hi.x, hi.y);
      aw.w = cvt_pk_bf16(hi.z, hi.w);
      bf16x8 af = __builtin_bit_cast(bf16x8, aw);
      acc0 = __builtin_amdgcn_mfma_f32_16x16x32_bf16(af, bfr[0][ks], acc0, 0, 0, 0);
      acc1 = __builtin_amdgcn_mfma_f32_16x16x32_bf16(af, bfr[1][ks], acc1, 0, 0, 0);
    }
#pragma unroll
    for (int k2 = 0; k2 < 4; ++k2) {
      bf16x8 xa = *(const bf16x8*)(xb + ((g * 16 + k2 * 64) ^ swz));
      acc0 = __builtin_amdgcn_mfma_f32_16x16x32_bf16(xa, bfr[0][4 + k2], acc0, 0, 0, 0);
      acc1 = __builtin_amdgcn_mfma_f32_16x16x32_bf16(xa, bfr[1][4 + k2], acc1, 0, 0, 0);
    }
#pragma unroll
    for (int r = 0; r < 4; ++r) {
      float s0 = acc0[r], s1 = acc1[r];
      sum0 += s0; ssq0 = fmaf(s0, s0, ssq0);
      mn0 = fminf(mn0, s0); mx0 = fmaxf(mx0, s0);
      sum1 += s1; ssq1 = fmaf(s1, s1, ssq1);
      mn1 = fminf(mn1, s1); mx1 = fmaxf(mx1, s1);
    }
  };

  STAGE(0); STAGE(1); STAGE(2);

#pragma unroll 1
  for (int t = 0; t < 13; ++t) {
    asm volatile("s_waitcnt vmcnt(6)" ::: "memory");   // tile t landed (3 ops/tile, 2 ahead)
    __builtin_amdgcn_s_barrier();
    __builtin_amdgcn_sched_barrier(0);
    STAGE(t + 3);
    __builtin_amdgcn_sched_barrier(0);
    COMPUTE(t);
  }
  asm volatile("s_waitcnt vmcnt(6)" ::: "memory");
  __builtin_amdgcn_s_barrier();
  __builtin_amdgcn_sched_barrier(0);
  COMPUTE(13);
  asm volatile("s_waitcnt vmcnt(3)" ::: "memory");
  __builtin_amdgcn_s_barrier();
  __builtin_amdgcn_sched_barrier(0);
  COMPUTE(14);
  asm volatile("s_waitcnt vmcnt(0)" ::: "memory");
  __builtin_amdgcn_s_barrier();
  __builtin_amdgcn_sched_barrier(0);
  COMPUTE(15);

  // reduce across the 4 row-groups (lane bits 4,5)
#pragma unroll
  for (int m = 16; m <= 32; m <<= 1) {
    sum0 += __shfl_xor(sum0, m); ssq0 += __shfl_xor(ssq0, m);
    mn0 = fminf(mn0, __shfl_xor(mn0, m)); mx0 = fmaxf(mx0, __shfl_xor(mx0, m));
    sum1 += __shfl_xor(sum1, m); ssq1 += __shfl_xor(ssq1, m);
    mn1 = fminf(mn1, __shfl_xor(mn1, m)); mx1 = fmaxf(mx1, __shfl_xor(mx1, m));
  }
  if (g == 0) {
#pragma unroll
    for (int t = 0; t < 2; ++t) {
      const int col = cb + t * 16 + lr;
      const float s   = t ? sum1 : sum0;
      const float q   = t ? ssq1 : ssq0;
      const float mnv = t ? mn1 : mn0;
      const float mxv = t ? mx1 : mx0;
      const float tt = At[blk * CC + col] + bc2[col];
      const float mean = s * (1.f / NB);
      const float var = q * (1.f / NB) - mean * mean;
      const float sd = sqrtf(fmaxf(var, 0.f) + 1e-5f);
      float* ap = agg + (size_t)blk * (4 * CC) + col;
      ap[0]      = tt + mean;
      ap[CC]     = tt + mnv;
      ap[2 * CC] = tt + mxv;
      ap[3 * CC] = sd;     // std is invariant to the j-constant term
    }
  }
}

// ---- k2: out = [x,agg]@W_post + b_post ; out@W_lin + b_lin ; per-block GN partials ----
// 512 blocks x 4 rows -> 2 blocks/CU, 2 waves/SIMD
__global__ __launch_bounds__(256) void k_post(
    const float* __restrict__ x, const float* __restrict__ agg,
    const float* __restrict__ W_post, const float* __restrict__ b_post,
    const float* __restrict__ W_lin, const float* __restrict__ b_lin,
    float* __restrict__ outl, float* __restrict__ psum, float* __restrict__ psq) {
  __shared__ float hx[4][5 * CC];
  __shared__ float o1[4][CC];
  __shared__ float pl[4][CC];
  const int blk = blockIdx.x;
  const int t = threadIdx.x;
  const int row0 = blk * 4;

  for (int idx = t; idx < 4 * 5 * CC; idx += 256) {
    int r = idx / (5 * CC), col = idx - r * (5 * CC);
    hx[r][col] = (col < CC) ? x[(size_t)(row0 + r) * CC + col]
                            : agg[(size_t)(row0 + r) * (4 * CC) + (col - CC)];
  }
  __syncthreads();

  const int c = t & (CC - 1);
  const int rh = t >> 7;  // 0/1
  float acc[2] = {b_post[c], b_post[c]};
  for (int k = 0; k < 5 * CC; k += 4) {
    float w0 = W_post[(k + 0) * CC + c];
    float w1 = W_post[(k + 1) * CC + c];
    float w2 = W_post[(k + 2) * CC + c];
    float w3 = W_post[(k + 3) * CC + c];
#pragma unroll
    for (int i = 0; i < 2; ++i) {
      const f32x4 h4 = *(const f32x4*)&hx[2 * i + rh][k];
      acc[i] += h4.x * w0 + h4.y * w1 + h4.z * w2 + h4.w * w3;
    }
  }
#pragma unroll
  for (int i = 0; i < 2; ++i) o1[2 * i + rh][c] = acc[i];
  __syncthreads();

  float a2[2] = {b_lin[c], b_lin[c]};
  for (int k = 0; k < CC; k += 4) {
    float w0 = W_lin[(k + 0) * CC + c];
    float w1 = W_lin[(k + 1) * CC + c];
    float w2 = W_lin[(k + 2) * CC + c];
    float w3 = W_lin[(k + 3) * CC + c];
#pragma unroll
    for (int i = 0; i < 2; ++i) {
      const f32x4 h4 = *(const f32x4*)&o1[2 * i + rh][k];
      a2[i] += h4.x * w0 + h4.y * w1 + h4.z * w2 + h4.w * w3;
    }
  }
  float ps = 0.f, pq = 0.f;
#pragma unroll
  for (int i = 0; i < 2; ++i) {
    outl[(size_t)(row0 + 2 * i + rh) * CC + c] = a2[i];
    ps += a2[i]; pq += a2[i] * a2[i];
  }
  pl[rh][c] = ps; pl[2 + rh][c] = pq;
  __syncthreads();
  if (t < CC) {
    psum[blk * CC + t] = pl[0][t] + pl[1][t];
    psq[blk * CC + t]  = pl[2][t] + pl[3][t];
  }
}

// ---- k3: fused GraphNorm stats + normalize + relu + residual ----
// 256 blocks; each block redundantly reduces the 512x128 partials, then applies 8 rows.
__global__ __launch_bounds__(256) void k_apply(
    const float* __restrict__ psum, const float* __restrict__ psq,
    const float* __restrict__ outl, const float* __restrict__ x,
    const float* __restrict__ gw, const float* __restrict__ gb,
    const float* __restrict__ alpha, float* __restrict__ y) {
  __shared__ float red[4][CC];
  __shared__ float smu[CC], siv[CC];
  const int t = threadIdx.x;
  const int c = t & (CC - 1);
  const int h = t >> 7;   // 0/1
  float s = 0.f, q = 0.f;
#pragma unroll 4
  for (int i = 0; i < 256; ++i) {
    const int r = h * 256 + i;
    s += psum[r * CC + c];
    q += psq[r * CC + c];
  }
  red[h][c] = s; red[2 + h][c] = q;
  __syncthreads();
  if (t < CC) {
    const float ss = red[0][t] + red[1][t];
    const float qq = red[2][t] + red[3][t];
    const float mu = ss * (1.f / 2048.f);
    const float ex2 = qq * (1.f / 2048.f);
    const float amu = alpha[t] * mu;
    const float v = ex2 - 2.f * amu * mu + amu * amu;
    smu[t] = amu;
    siv[t] = gw[t] / sqrtf(v + 1e-5f);
  }
  __syncthreads();
  const int row0 = blockIdx.x * 8;
#pragma unroll
  for (int r = 0; r < 8; r += 2) {
    const int idx = (row0 + r + h) * CC + c;
    const float o = outl[idx];
    const float val = (o - smu[c]) * siv[c] + gb[c];
    y[idx] = fmaxf(val, 0.f) + x[idx];
  }
}

extern "C" void kernel_launch(void* const* d_in, const int* in_sizes, int n_in,
                              void* d_out, int out_size, void* d_ws, size_t ws_size,
                              hipStream_t stream) {
  const float* x      = (const float*)d_in[0];
  const float* edge   = (const float*)d_in[1];
  const float* W_edge = (const float*)d_in[2];
  const float* b_edge = (const float*)d_in[3];
  const float* W_pre  = (const float*)d_in[4];
  const float* b_pre  = (const float*)d_in[5];
  const float* W_post = (const float*)d_in[6];
  const float* b_post = (const float*)d_in[7];
  const float* W_lin  = (const float*)d_in[8];
  const float* b_lin  = (const float*)d_in[9];
  const float* gw     = (const float*)d_in[10];
  const float* gb     = (const float*)d_in[11];
  const float* alpha  = (const float*)d_in[12];
  float* y = (float*)d_out;

  float* wsf = (float*)d_ws;
  float* bc2   = wsf;                 // 128
  float* At    = wsf + 128;           // 2048*128
  float* agg   = wsf + 262272;        // 2048*512
  float* outl  = wsf + 1310848;       // 2048*128
  float* psum  = wsf + 1572992;       // 512*128
  float* psq   = wsf + 1638528;       // 512*128
  uint16_t* wct = (uint16_t*)(wsf + 1704064);  // 128*128 bf16
  uint16_t* w2t = (uint16_t*)(wsf + 1712256);  // 128*128 bf16
  uint16_t* xbf = (uint16_t*)(wsf + 1720448);  // 2048*128 bf16

  k_prep<<<2176, 128, 0, stream>>>(W_edge, b_edge, W_pre, b_pre, x, wct, w2t, bc2, At, xbf);
  k_edge<<<2048, 256, 0, stream>>>(edge, wct, w2t, xbf, At, bc2, agg);
  k_post<<<512, 256, 0, stream>>>(x, agg, W_post, b_post, W_lin, b_lin, outl, psum, psq);
  k_apply<<<256, 256, 0, stream>>>(psum, psq, outl, x, gw, gb, alpha, y);
}

// Round 5
// 107.828 us; speedup vs baseline: 2.0671x; 1.0477x over previous
//
#include <hip/hip_runtime.h>
#include <hip/hip_bf16.h>
#include <stdint.h>

typedef __attribute__((ext_vector_type(8))) short bf16x8;
typedef __attribute__((ext_vector_type(4))) float f32x4;
typedef __attribute__((ext_vector_type(4))) unsigned int u32x4;

#define NB 256
#define CC 128

typedef const __attribute__((address_space(1))) void* gvp;
typedef __attribute__((address_space(3))) void* lvp;
#define GLOAD_LDS16(GP, LP) \
  __builtin_amdgcn_global_load_lds((gvp)(uintptr_t)(GP), (lvp)(uintptr_t)(LP), 16, 0, 0)

static __device__ __forceinline__ unsigned int cvt_pk_bf16(float lo, float hi) {
  unsigned int r;
  asm("v_cvt_pk_bf16_f32 %0, %1, %2" : "=v"(r) : "v"(lo), "v"(hi));
  return r;
}
static __device__ __forceinline__ uint16_t f2bf(float f) {
  unsigned u = __builtin_bit_cast(unsigned, f);
  return (uint16_t)((u + 0x7FFFu + ((u >> 16) & 1u)) >> 16);
}

// ---- k_prep (fused): blocks 0..127 weight prep; blocks 128..1151 node prep (2 rows each)
__global__ void k_prep(const float* __restrict__ W_edge, const float* __restrict__ b_edge,
                       const float* __restrict__ W_pre, const float* __restrict__ b_pre,
                       const float* __restrict__ x,
                       uint16_t* __restrict__ wct, float* __restrict__ bc2,
                       float* __restrict__ At, float* __restrict__ Bv) {
  const int c = threadIdx.x;  // 0..127
  if (blockIdx.x < 128) {
    const int k = blockIdx.x;   // input channel
    float acc = 0.f;
    for (int q = 0; q < CC; ++q)
      acc += W_edge[k * CC + q] * W_pre[(2 * CC + q) * CC + c];
    wct[c * CC + k] = f2bf(acc);                        // (W_edge@W3)^T, bf16
    if (k == 0) {
      float a2 = b_pre[c];
      for (int q = 0; q < CC; ++q) a2 += b_edge[q] * W_pre[(2 * CC + q) * CC + c];
      bc2[c] = a2;
    }
  } else {
    const int m0 = (blockIdx.x - 128) * 2;   // 2 node rows per block
    __shared__ float xs[2][CC];
    xs[0][c] = x[(size_t)m0 * CC + c];
    xs[1][c] = x[(size_t)(m0 + 1) * CC + c];
    __syncthreads();
    float a0 = 0.f, a1 = 0.f, v0 = 0.f, v1 = 0.f;
#pragma unroll 4
    for (int k = 0; k < CC; ++k) {
      const float w1 = W_pre[k * CC + c];
      const float w2 = W_pre[(CC + k) * CC + c];
      a0 += xs[0][k] * w1; a1 += xs[1][k] * w1;
      v0 += xs[0][k] * w2; v1 += xs[1][k] * w2;
    }
    At[(size_t)m0 * CC + c] = a0;       At[(size_t)(m0 + 1) * CC + c] = a1;
    Bv[(size_t)m0 * CC + c] = v0;       Bv[(size_t)(m0 + 1) * CC + c] = v1;
  }
}

// ---- k1: fused edge-GEMM (K=128, bf16 MFMA) + fp32 Bv add + PNA reduction ----
// LDS: 3 e-buffers (8 KB) + 2 bv-buffers (8 KB) = 40 KB -> 4 blocks/CU, 16 waves/CU.
__global__ __launch_bounds__(256, 4) void k_edge(
    const float* __restrict__ edge, const uint16_t* __restrict__ wct,
    const float* __restrict__ Bv, const float* __restrict__ At,
    const float* __restrict__ bc2, float* __restrict__ agg) {
  __shared__ __align__(16) float ebuf[3][2048];    // 16 j-rows x 128 k fp32, swizzled
  __shared__ __align__(16) float bvbuf[2][2048];   // 16 j-rows x 128 c fp32, swizzled

  const int blk  = blockIdx.x;         // b*256 + i
  const int b    = blk >> 8;
  const int tid  = threadIdx.x;
  const int lane = tid & 63;
  const int wv   = tid >> 6;           // 0..3
  const int g    = lane >> 4;          // 0..3
  const int lr   = lane & 15;
  const int cb   = wv * 32;            // 32 output channels per wave

  // Resident B fragments: (W_edge@W3)^T rows = output channels, 8 contiguous k/lane
  bf16x8 bfr[2][4];
#pragma unroll
  for (int t = 0; t < 2; ++t) {
    const uint16_t* p1 = wct + (cb + t * 16 + lr) * CC + g * 8;
#pragma unroll
    for (int ks = 0; ks < 4; ++ks)
      bfr[t][ks] = *(const bf16x8*)(p1 + ks * 32);
  }
  // drain bfr loads so the vmcnt FIFO holds ONLY stage ops from here on
  asm volatile("s_waitcnt vmcnt(0)" ::: "memory");

  // staging source offsets: per-lane linear offset within an 8 KB tile, swizzle
  // pre-applied to the SOURCE (LDS dest stays linear; read side applies same XOR)
  const uint32_t L0 = wv * 2048 + lane * 16;
  const uint32_t L1 = L0 + 1024;
  const uint32_t S0 = L0 ^ (((L0 >> 9) & 7) << 4);
  const uint32_t S1 = L1 ^ (((L1 >> 9) & 7) << 4);

  const char* egbase  = (const char*)(edge + (size_t)blk * (NB * CC));
  const char* bvgbase = (const char*)(Bv + (size_t)b * (NB * CC));

  auto STAGE_E = [&](int buf, int t) {
    const char* eg = egbase + (size_t)t * 8192;
    char* el = (char*)&ebuf[buf][0];
    GLOAD_LDS16(eg + S0, el + wv * 2048);
    GLOAD_LDS16(eg + S1, el + wv * 2048 + 1024);
  };
  auto STAGE_BV = [&](int buf, int t) {
    const char* bg = bvgbase + (size_t)t * 8192;
    char* bl = (char*)&bvbuf[buf][0];
    GLOAD_LDS16(bg + S0, bl + wv * 2048);
    GLOAD_LDS16(bg + S1, bl + wv * 2048 + 1024);
  };

  float sum0 = 0.f, sum1 = 0.f, ssq0 = 0.f, ssq1 = 0.f;
  float mn0 = 1e30f, mn1 = 1e30f, mx0 = -1e30f, mx1 = -1e30f;
  const int swz = (lr & 7) << 4;

  auto COMPUTE = [&](int ebi, int bvi) {
    const char* eb = (const char*)&ebuf[ebi][0] + lr * 512;
    const char* bb = (const char*)&bvbuf[bvi][0];
    f32x4 acc0 = {0.f, 0.f, 0.f, 0.f}, acc1 = {0.f, 0.f, 0.f, 0.f};
#pragma unroll
    for (int ks = 0; ks < 4; ++ks) {
      const int off = g * 32 + ks * 128;
      f32x4 lo = *(const f32x4*)(eb + (off ^ swz));
      f32x4 hi = *(const f32x4*)(eb + ((off + 16) ^ swz));
      u32x4 aw;
      aw.x = cvt_pk_bf16(lo.x, lo.y);
      aw.y = cvt_pk_bf16(lo.z, lo.w);
      aw.z = cvt_pk_bf16(hi.x, hi.y);
      aw.w = cvt_pk_bf16(hi.z, hi.w);
      bf16x8 af = __builtin_bit_cast(bf16x8, aw);
      acc0 = __builtin_amdgcn_mfma_f32_16x16x32_bf16(af, bfr[0][ks], acc0, 0, 0, 0);
      acc1 = __builtin_amdgcn_mfma_f32_16x16x32_bf16(af, bfr[1][ks], acc1, 0, 0, 0);
    }
#pragma unroll
    for (int r = 0; r < 4; ++r) {
      const int row = g * 4 + r;
      const int sw = (row & 7) << 4;
      const int lin0 = row * 512 + (cb + lr) * 4;
      const float bv0 = *(const float*)(bb + (lin0 ^ sw));
      const float bv1 = *(const float*)(bb + ((lin0 + 64) ^ sw));
      float s0 = acc0[r] + bv0;
      float s1 = acc1[r] + bv1;
      sum0 += s0; ssq0 = fmaf(s0, s0, ssq0);
      mn0 = fminf(mn0, s0); mx0 = fmaxf(mx0, s0);
      sum1 += s1; ssq1 = fmaf(s1, s1, ssq1);
      mn1 = fminf(mn1, s1); mx1 = fmaxf(mx1, s1);
    }
  };

  // prologue: FIFO = e0(2), bv0(2), e1(2)
  STAGE_E(0, 0); STAGE_BV(0, 0); STAGE_E(1, 1);

  int eu = 0;   // t % 3
  int bu = 0;   // t & 1
#pragma unroll 1
  for (int t = 0; t < 14; ++t) {
    // wait for bv(t) [and transitively e(t)]; leaves e(t+1) in flight
    asm volatile("s_waitcnt vmcnt(2)" ::: "memory");
    __builtin_amdgcn_s_barrier();
    __builtin_amdgcn_sched_barrier(0);
    int esb = eu - 1; if (esb < 0) esb = 2;     // (t+2) % 3
    STAGE_BV(bu ^ 1, t + 1);
    STAGE_E(esb, t + 2);
    __builtin_amdgcn_sched_barrier(0);
    COMPUTE(eu, bu);
    eu = (eu == 2) ? 0 : eu + 1;
    bu ^= 1;
  }
  // t = 14: stages only bv(15)
  asm volatile("s_waitcnt vmcnt(2)" ::: "memory");
  __builtin_amdgcn_s_barrier();
  __builtin_amdgcn_sched_barrier(0);
  STAGE_BV(1, 15);
  __builtin_amdgcn_sched_barrier(0);
  COMPUTE(2, 0);
  // t = 15
  asm volatile("s_waitcnt vmcnt(0)" ::: "memory");
  __builtin_amdgcn_s_barrier();
  __builtin_amdgcn_sched_barrier(0);
  COMPUTE(0, 1);

  // reduce across the 4 row-groups (lane bits 4,5)
#pragma unroll
  for (int m = 16; m <= 32; m <<= 1) {
    sum0 += __shfl_xor(sum0, m); ssq0 += __shfl_xor(ssq0, m);
    mn0 = fminf(mn0, __shfl_xor(mn0, m)); mx0 = fmaxf(mx0, __shfl_xor(mx0, m));
    sum1 += __shfl_xor(sum1, m); ssq1 += __shfl_xor(ssq1, m);
    mn1 = fminf(mn1, __shfl_xor(mn1, m)); mx1 = fmaxf(mx1, __shfl_xor(mx1, m));
  }
  if (g == 0) {
#pragma unroll
    for (int t = 0; t < 2; ++t) {
      const int col = cb + t * 16 + lr;
      const float s   = t ? sum1 : sum0;
      const float q   = t ? ssq1 : ssq0;
      const float mnv = t ? mn1 : mn0;
      const float mxv = t ? mx1 : mx0;
      const float tt = At[blk * CC + col] + bc2[col];
      const float mean = s * (1.f / NB);
      const float var = q * (1.f / NB) - mean * mean;
      const float sd = sqrtf(fmaxf(var, 0.f) + 1e-5f);
      float* ap = agg + (size_t)blk * (4 * CC) + col;
      ap[0]      = tt + mean;
      ap[CC]     = tt + mnv;
      ap[2 * CC] = tt + mxv;
      ap[3 * CC] = sd;     // std is invariant to the j-constant term
    }
  }
}

// ---- k2: out = [x,agg]@W_post + b_post ; out@W_lin + b_lin ; per-block GN partials ----
__global__ __launch_bounds__(256) void k_post(
    const float* __restrict__ x, const float* __restrict__ agg,
    const float* __restrict__ W_post, const float* __restrict__ b_post,
    const float* __restrict__ W_lin, const float* __restrict__ b_lin,
    float* __restrict__ outl, float* __restrict__ psum, float* __restrict__ psq) {
  __shared__ float hx[4][5 * CC];
  __shared__ float o1[4][CC];
  __shared__ float pl[4][CC];
  const int blk = blockIdx.x;
  const int t = threadIdx.x;
  const int row0 = blk * 4;

  for (int idx = t; idx < 4 * 5 * CC; idx += 256) {
    int r = idx / (5 * CC), col = idx - r * (5 * CC);
    hx[r][col] = (col < CC) ? x[(size_t)(row0 + r) * CC + col]
                            : agg[(size_t)(row0 + r) * (4 * CC) + (col - CC)];
  }
  __syncthreads();

  const int c = t & (CC - 1);
  const int rh = t >> 7;  // 0/1
  float acc[2] = {b_post[c], b_post[c]};
  for (int k = 0; k < 5 * CC; k += 4) {
    float w0 = W_post[(k + 0) * CC + c];
    float w1 = W_post[(k + 1) * CC + c];
    float w2 = W_post[(k + 2) * CC + c];
    float w3 = W_post[(k + 3) * CC + c];
#pragma unroll
    for (int i = 0; i < 2; ++i) {
      const f32x4 h4 = *(const f32x4*)&hx[2 * i + rh][k];
      acc[i] += h4.x * w0 + h4.y * w1 + h4.z * w2 + h4.w * w3;
    }
  }
#pragma unroll
  for (int i = 0; i < 2; ++i) o1[2 * i + rh][c] = acc[i];
  __syncthreads();

  float a2[2] = {b_lin[c], b_lin[c]};
  for (int k = 0; k < CC; k += 4) {
    float w0 = W_lin[(k + 0) * CC + c];
    float w1 = W_lin[(k + 1) * CC + c];
    float w2 = W_lin[(k + 2) * CC + c];
    float w3 = W_lin[(k + 3) * CC + c];
#pragma unroll
    for (int i = 0; i < 2; ++i) {
      const f32x4 h4 = *(const f32x4*)&o1[2 * i + rh][k];
      a2[i] += h4.x * w0 + h4.y * w1 + h4.z * w2 + h4.w * w3;
    }
  }
  float ps = 0.f, pq = 0.f;
#pragma unroll
  for (int i = 0; i < 2; ++i) {
    outl[(size_t)(row0 + 2 * i + rh) * CC + c] = a2[i];
    ps += a2[i]; pq += a2[i] * a2[i];
  }
  pl[rh][c] = ps; pl[2 + rh][c] = pq;
  __syncthreads();
  if (t < CC) {
    psum[blk * CC + t] = pl[0][t] + pl[1][t];
    psq[blk * CC + t]  = pl[2][t] + pl[3][t];
  }
}

// ---- k3: fused GraphNorm stats + normalize + relu + residual ----
__global__ __launch_bounds__(256) void k_apply(
    const float* __restrict__ psum, const float* __restrict__ psq,
    const float* __restrict__ outl, const float* __restrict__ x,
    const float* __restrict__ gw, const float* __restrict__ gb,
    const float* __restrict__ alpha, float* __restrict__ y) {
  __shared__ float red[4][CC];
  __shared__ float smu[CC], siv[CC];
  const int t = threadIdx.x;
  const int c = t & (CC - 1);
  const int h = t >> 7;   // 0/1
  float s = 0.f, q = 0.f;
#pragma unroll 4
  for (int i = 0; i < 256; ++i) {
    const int r = h * 256 + i;
    s += psum[r * CC + c];
    q += psq[r * CC + c];
  }
  red[h][c] = s; red[2 + h][c] = q;
  __syncthreads();
  if (t < CC) {
    const float ss = red[0][t] + red[1][t];
    const float qq = red[2][t] + red[3][t];
    const float mu = ss * (1.f / 2048.f);
    const float ex2 = qq * (1.f / 2048.f);
    const float amu = alpha[t] * mu;
    const float v = ex2 - 2.f * amu * mu + amu * amu;
    smu[t] = amu;
    siv[t] = gw[t] / sqrtf(v + 1e-5f);
  }
  __syncthreads();
  const int row0 = blockIdx.x * 8;
#pragma unroll
  for (int r = 0; r < 8; r += 2) {
    const int idx = (row0 + r + h) * CC + c;
    const float o = outl[idx];
    const float val = (o - smu[c]) * siv[c] + gb[c];
    y[idx] = fmaxf(val, 0.f) + x[idx];
  }
}

extern "C" void kernel_launch(void* const* d_in, const int* in_sizes, int n_in,
                              void* d_out, int out_size, void* d_ws, size_t ws_size,
                              hipStream_t stream) {
  const float* x      = (const float*)d_in[0];
  const float* edge   = (const float*)d_in[1];
  const float* W_edge = (const float*)d_in[2];
  const float* b_edge = (const float*)d_in[3];
  const float* W_pre  = (const float*)d_in[4];
  const float* b_pre  = (const float*)d_in[5];
  const float* W_post = (const float*)d_in[6];
  const float* b_post = (const float*)d_in[7];
  const float* W_lin  = (const float*)d_in[8];
  const float* b_lin  = (const float*)d_in[9];
  const float* gw     = (const float*)d_in[10];
  const float* gb     = (const float*)d_in[11];
  const float* alpha  = (const float*)d_in[12];
  float* y = (float*)d_out;

  float* wsf = (float*)d_ws;
  float* bc2   = wsf;                 // 128
  float* At    = wsf + 128;           // 2048*128
  float* Bv    = wsf + 262272;        // 2048*128
  float* agg   = wsf + 524416;        // 2048*512
  float* outl  = wsf + 1572992;       // 2048*128
  float* psum  = wsf + 1835136;       // 512*128
  float* psq   = wsf + 1900672;       // 512*128
  uint16_t* wct = (uint16_t*)(wsf + 1966208);  // 128*128 bf16

  k_prep<<<1152, 128, 0, stream>>>(W_edge, b_edge, W_pre, b_pre, x, wct, bc2, At, Bv);
  k_edge<<<2048, 256, 0, stream>>>(edge, wct, Bv, At, bc2, agg);
  k_post<<<512, 256, 0, stream>>>(x, agg, W_post, b_post, W_lin, b_lin, outl, psum, psq);
  k_apply<<<256, 256, 0, stream>>>(psum, psq, outl, x, gw, gb, alpha, y);
}

// Round 7
// 106.667 us; speedup vs baseline: 2.0896x; 1.0109x over previous
//
#include <hip/hip_runtime.h>
#include <hip/hip_bf16.h>
#include <stdint.h>

typedef __attribute__((ext_vector_type(8))) short bf16x8;
typedef __attribute__((ext_vector_type(4))) float f32x4;
typedef __attribute__((ext_vector_type(4))) unsigned int u32x4;

#define NB 256
#define CC 128

static __device__ __forceinline__ unsigned int cvt_pk_bf16(float lo, float hi) {
  unsigned int r;
  asm("v_cvt_pk_bf16_f32 %0, %1, %2" : "=v"(r) : "v"(lo), "v"(hi));
  return r;
}
static __device__ __forceinline__ uint16_t f2bf(float f) {
  unsigned u = __builtin_bit_cast(unsigned, f);
  return (uint16_t)((u + 0x7FFFu + ((u >> 16) & 1u)) >> 16);
}

// ---- k_prep: blocks 0..127 weight prep; blocks 128..1151 node prep (2 rows each)
// Outputs: wct bf16 (W_edge@W3)^T; bc2; At = x@W1 (fp32); bvl = bf16-pair packed x@W2.
__global__ void k_prep(const float* __restrict__ W_edge, const float* __restrict__ b_edge,
                       const float* __restrict__ W_pre, const float* __restrict__ b_pre,
                       const float* __restrict__ x,
                       uint16_t* __restrict__ wct, float* __restrict__ bc2,
                       float* __restrict__ At, unsigned* __restrict__ bvl) {
  const int c = threadIdx.x;  // 0..127
  if (blockIdx.x < 128) {
    const int k = blockIdx.x;   // input channel
    float acc = 0.f;
    for (int q = 0; q < CC; ++q)
      acc += W_edge[k * CC + q] * W_pre[(2 * CC + q) * CC + c];
    wct[c * CC + k] = f2bf(acc);                        // (W_edge@W3)^T, bf16
    if (k == 0) {
      float a2 = b_pre[c];
      for (int q = 0; q < CC; ++q) a2 += b_edge[q] * W_pre[(2 * CC + q) * CC + c];
      bc2[c] = a2;
    }
  } else {
    const int m0 = (blockIdx.x - 128) * 2;   // 2 node rows per block
    __shared__ float xs[2][CC];
    xs[0][c] = x[(size_t)m0 * CC + c];
    xs[1][c] = x[(size_t)(m0 + 1) * CC + c];
    __syncthreads();
    float a0 = 0.f, a1 = 0.f, v0 = 0.f, v1 = 0.f;
#pragma unroll 4
    for (int k = 0; k < CC; ++k) {
      const float w1 = W_pre[k * CC + c];
      const float w2 = W_pre[(CC + k) * CC + c];
      a0 += xs[0][k] * w1; a1 += xs[1][k] * w1;
      v0 += xs[0][k] * w2; v1 += xs[1][k] * w2;
    }
    At[(size_t)m0 * CC + c] = a0;       At[(size_t)(m0 + 1) * CC + c] = a1;
    // pack bvl[row][wv(2b)][lr(4b)] = {bf16(ch=wv*32+lr), bf16(ch=wv*32+16+lr)}
    const float p0 = __shfl_down(v0, 16);
    const float p1 = __shfl_down(v1, 16);
    if ((c & 31) < 16) {
      const int di = (c >> 5) * 16 + (c & 15);
      bvl[(size_t)m0 * 64 + di]       = ((unsigned)f2bf(p0) << 16) | f2bf(v0);
      bvl[(size_t)(m0 + 1) * 64 + di] = ((unsigned)f2bf(p1) << 16) | f2bf(v1);
    }
  }
}

// ---- k1: fused edge-GEMM (bf16 MFMA) + bv add + PNA reduction over j ----
// Reg-staged: global fp32 -> cvt bf16 -> padded LDS (272 B/row, conflict-free b128).
// LDS: 2 x 4.25 KB (e) + 2 x 4.25 KB (bv) = 17 KB -> 4 blocks/CU.
__global__ __launch_bounds__(256, 4) void k_edge(
    const float* __restrict__ edge, const uint16_t* __restrict__ wct,
    const unsigned* __restrict__ bvl, const float* __restrict__ At,
    const float* __restrict__ bc2, float* __restrict__ agg) {
  __shared__ __align__(16) char ebuf[2][16 * 272];    // 16 rows x 128 bf16, padded
  __shared__ __align__(16) char bvbuf[2][16 * 272];   // 16 rows x 64 u32 pairs, padded

  const int blk  = blockIdx.x;         // b*256 + i
  const int b    = blk >> 8;
  const int tid  = threadIdx.x;
  const int lane = tid & 63;
  const int wv   = tid >> 6;           // 0..3
  const int g    = lane >> 4;          // 0..3
  const int lr   = lane & 15;
  const int cb   = wv * 32;            // 32 output channels per wave

  // Resident B fragments from wct (unchanged layout, verified)
  bf16x8 bfr[2][4];
#pragma unroll
  for (int t = 0; t < 2; ++t) {
    const uint16_t* p1 = wct + (cb + t * 16 + lr) * CC + g * 8;
#pragma unroll
    for (int ks = 0; ks < 4; ++ks)
      bfr[t][ks] = *(const bf16x8*)(p1 + ks * 32);
  }
  asm volatile("s_waitcnt vmcnt(0)" ::: "memory");   // FIFO now holds only stage loads

  const char* egbase  = (const char*)(edge + (size_t)blk * (NB * CC));
  const char* bvgbase = (const char*)(bvl + (size_t)b * (NB * 64));
  const int sdst = (tid >> 4) * 272 + (tid & 15) * 16;   // LDS dest, both tiles

  f32x4 eA0, eA1, eB0, eB1;
  u32x4 vA, vB;

  auto LOADA = [&](int t) {
    const f32x4* s = (const f32x4*)(egbase + (size_t)t * 8192 + tid * 32);
    eA0 = s[0]; eA1 = s[1];
    vA = *(const u32x4*)(bvgbase + (size_t)t * 4096 + tid * 16);
  };
  auto LOADB = [&](int t) {
    const f32x4* s = (const f32x4*)(egbase + (size_t)t * 8192 + tid * 32);
    eB0 = s[0]; eB1 = s[1];
    vB = *(const u32x4*)(bvgbase + (size_t)t * 4096 + tid * 16);
  };
  auto STORE = [&](char* eb_, char* bb_, const f32x4& e0, const f32x4& e1, const u32x4& v) {
    u32x4 w;
    w.x = cvt_pk_bf16(e0.x, e0.y); w.y = cvt_pk_bf16(e0.z, e0.w);
    w.z = cvt_pk_bf16(e1.x, e1.y); w.w = cvt_pk_bf16(e1.z, e1.w);
    *(u32x4*)(eb_ + sdst) = w;
    *(u32x4*)(bb_ + sdst) = v;
  };

  float sum0 = 0.f, sum1 = 0.f, ssq0 = 0.f, ssq1 = 0.f;
  float mn0 = 1e30f, mn1 = 1e30f, mx0 = -1e30f, mx1 = -1e30f;

  auto COMPUTE = [&](const char* eb_, const char* bb_) {
    const char* eb = eb_ + lr * 272;
    f32x4 acc0 = {0.f, 0.f, 0.f, 0.f}, acc1 = {0.f, 0.f, 0.f, 0.f};
#pragma unroll
    for (int ks = 0; ks < 4; ++ks) {
      bf16x8 af = *(const bf16x8*)(eb + g * 16 + ks * 64);
      acc0 = __builtin_amdgcn_mfma_f32_16x16x32_bf16(af, bfr[0][ks], acc0, 0, 0, 0);
      acc1 = __builtin_amdgcn_mfma_f32_16x16x32_bf16(af, bfr[1][ks], acc1, 0, 0, 0);
    }
#pragma unroll
    for (int r = 0; r < 4; ++r) {
      const int row = g * 4 + r;
      const unsigned pv = *(const unsigned*)(bb_ + row * 272 + wv * 64 + lr * 4);
      const float bv0 = __builtin_bit_cast(float, pv << 16);
      const float bv1 = __builtin_bit_cast(float, pv & 0xffff0000u);
      float s0 = acc0[r] + bv0;
      float s1 = acc1[r] + bv1;
      sum0 += s0; ssq0 = fmaf(s0, s0, ssq0);
      mn0 = fminf(mn0, s0); mx0 = fmaxf(mx0, s0);
      sum1 += s1; ssq1 = fmaf(s1, s1, ssq1);
      mn1 = fminf(mn1, s1); mx1 = fmaxf(mx1, s1);
    }
  };

  LOADA(0); LOADB(1);
  __builtin_amdgcn_sched_barrier(0);

#pragma unroll 1
  for (int tt = 0; tt < 16; tt += 2) {
    // ---- tile tt : regs A -> buf0
    __builtin_amdgcn_s_barrier();                       // WAR: buf0 free
    asm volatile("s_waitcnt vmcnt(3)" ::: "memory");    // A landed (B in flight)
    __builtin_amdgcn_sched_barrier(0);
    STORE(ebuf[0], bvbuf[0], eA0, eA1, vA);
    asm volatile("s_waitcnt lgkmcnt(0)" ::: "memory");
    __builtin_amdgcn_sched_barrier(0);
    __builtin_amdgcn_s_barrier();                       // RAW: buf0 visible
    if (tt + 2 < 16) LOADA(tt + 2);
    __builtin_amdgcn_sched_barrier(0);
    COMPUTE(ebuf[0], bvbuf[0]);
    // ---- tile tt+1 : regs B -> buf1
    __builtin_amdgcn_s_barrier();                       // WAR: buf1 free
    if (tt < 14) { asm volatile("s_waitcnt vmcnt(3)" ::: "memory"); }
    else         { asm volatile("s_waitcnt vmcnt(0)" ::: "memory"); }
    __builtin_amdgcn_sched_barrier(0);
    STORE(ebuf[1], bvbuf[1], eB0, eB1, vB);
    asm volatile("s_waitcnt lgkmcnt(0)" ::: "memory");
    __builtin_amdgcn_sched_barrier(0);
    __builtin_amdgcn_s_barrier();                       // RAW: buf1 visible
    if (tt + 3 < 16) LOADB(tt + 3);
    __builtin_amdgcn_sched_barrier(0);
    COMPUTE(ebuf[1], bvbuf[1]);
  }

  // reduce across the 4 row-groups (lane bits 4,5)
#pragma unroll
  for (int m = 16; m <= 32; m <<= 1) {
    sum0 += __shfl_xor(sum0, m); ssq0 += __shfl_xor(ssq0, m);
    mn0 = fminf(mn0, __shfl_xor(mn0, m)); mx0 = fmaxf(mx0, __shfl_xor(mx0, m));
    sum1 += __shfl_xor(sum1, m); ssq1 += __shfl_xor(ssq1, m);
    mn1 = fminf(mn1, __shfl_xor(mn1, m)); mx1 = fmaxf(mx1, __shfl_xor(mx1, m));
  }
  if (g == 0) {
#pragma unroll
    for (int t = 0; t < 2; ++t) {
      const int col = cb + t * 16 + lr;
      const float s   = t ? sum1 : sum0;
      const float q   = t ? ssq1 : ssq0;
      const float mnv = t ? mn1 : mn0;
      const float mxv = t ? mx1 : mx0;
      const float tt2 = At[blk * CC + col] + bc2[col];
      const float mean = s * (1.f / NB);
      const float var = q * (1.f / NB) - mean * mean;
      const float sd = sqrtf(fmaxf(var, 0.f) + 1e-5f);
      float* ap = agg + (size_t)blk * (4 * CC) + col;
      ap[0]      = tt2 + mean;
      ap[CC]     = tt2 + mnv;
      ap[2 * CC] = tt2 + mxv;
      ap[3 * CC] = sd;     // std is invariant to the j-constant term
    }
  }
}

// ---- k2: out = [x,agg]@W_post + b_post ; out@W_lin + b_lin ; per-block GN partials ----
__global__ __launch_bounds__(256) void k_post(
    const float* __restrict__ x, const float* __restrict__ agg,
    const float* __restrict__ W_post, const float* __restrict__ b_post,
    const float* __restrict__ W_lin, const float* __restrict__ b_lin,
    float* __restrict__ outl, float* __restrict__ psum, float* __restrict__ psq) {
  __shared__ float hx[4][5 * CC];
  __shared__ float o1[4][CC];
  __shared__ float pl[4][CC];
  const int blk = blockIdx.x;
  const int t = threadIdx.x;
  const int row0 = blk * 4;

  for (int idx = t; idx < 4 * 5 * CC; idx += 256) {
    int r = idx / (5 * CC), col = idx - r * (5 * CC);
    hx[r][col] = (col < CC) ? x[(size_t)(row0 + r) * CC + col]
                            : agg[(size_t)(row0 + r) * (4 * CC) + (col - CC)];
  }
  __syncthreads();

  const int c = t & (CC - 1);
  const int rh = t >> 7;  // 0/1
  float acc[2] = {b_post[c], b_post[c]};
  for (int k = 0; k < 5 * CC; k += 4) {
    float w0 = W_post[(k + 0) * CC + c];
    float w1 = W_post[(k + 1) * CC + c];
    float w2 = W_post[(k + 2) * CC + c];
    float w3 = W_post[(k + 3) * CC + c];
#pragma unroll
    for (int i = 0; i < 2; ++i) {
      const f32x4 h4 = *(const f32x4*)&hx[2 * i + rh][k];
      acc[i] += h4.x * w0 + h4.y * w1 + h4.z * w2 + h4.w * w3;
    }
  }
#pragma unroll
  for (int i = 0; i < 2; ++i) o1[2 * i + rh][c] = acc[i];
  __syncthreads();

  float a2[2] = {b_lin[c], b_lin[c]};
  for (int k = 0; k < CC; k += 4) {
    float w0 = W_lin[(k + 0) * CC + c];
    float w1 = W_lin[(k + 1) * CC + c];
    float w2 = W_lin[(k + 2) * CC + c];
    float w3 = W_lin[(k + 3) * CC + c];
#pragma unroll
    for (int i = 0; i < 2; ++i) {
      const f32x4 h4 = *(const f32x4*)&o1[2 * i + rh][k];
      a2[i] += h4.x * w0 + h4.y * w1 + h4.z * w2 + h4.w * w3;
    }
  }
  float ps = 0.f, pq = 0.f;
#pragma unroll
  for (int i = 0; i < 2; ++i) {
    outl[(size_t)(row0 + 2 * i + rh) * CC + c] = a2[i];
    ps += a2[i]; pq += a2[i] * a2[i];
  }
  pl[rh][c] = ps; pl[2 + rh][c] = pq;
  __syncthreads();
  if (t < CC) {
    psum[blk * CC + t] = pl[0][t] + pl[1][t];
    psq[blk * CC + t]  = pl[2][t] + pl[3][t];
  }
}

// ---- k3: fused GraphNorm stats + normalize + relu + residual ----
__global__ __launch_bounds__(256) void k_apply(
    const float* __restrict__ psum, const float* __restrict__ psq,
    const float* __restrict__ outl, const float* __restrict__ x,
    const float* __restrict__ gw, const float* __restrict__ gb,
    const float* __restrict__ alpha, float* __restrict__ y) {
  __shared__ float red[4][CC];
  __shared__ float smu[CC], siv[CC];
  const int t = threadIdx.x;
  const int c = t & (CC - 1);
  const int h = t >> 7;   // 0/1
  float s = 0.f, q = 0.f;
#pragma unroll 4
  for (int i = 0; i < 256; ++i) {
    const int r = h * 256 + i;
    s += psum[r * CC + c];
    q += psq[r * CC + c];
  }
  red[h][c] = s; red[2 + h][c] = q;
  __syncthreads();
  if (t < CC) {
    const float ss = red[0][t] + red[1][t];
    const float qq = red[2][t] + red[3][t];
    const float mu = ss * (1.f / 2048.f);
    const float ex2 = qq * (1.f / 2048.f);
    const float amu = alpha[t] * mu;
    const float v = ex2 - 2.f * amu * mu + amu * amu;
    smu[t] = amu;
    siv[t] = gw[t] / sqrtf(v + 1e-5f);
  }
  __syncthreads();
  const int row0 = blockIdx.x * 8;
#pragma unroll
  for (int r = 0; r < 8; r += 2) {
    const int idx = (row0 + r + h) * CC + c;
    const float o = outl[idx];
    const float val = (o - smu[c]) * siv[c] + gb[c];
    y[idx] = fmaxf(val, 0.f) + x[idx];
  }
}

extern "C" void kernel_launch(void* const* d_in, const int* in_sizes, int n_in,
                              void* d_out, int out_size, void* d_ws, size_t ws_size,
                              hipStream_t stream) {
  const float* x      = (const float*)d_in[0];
  const float* edge   = (const float*)d_in[1];
  const float* W_edge = (const float*)d_in[2];
  const float* b_edge = (const float*)d_in[3];
  const float* W_pre  = (const float*)d_in[4];
  const float* b_pre  = (const float*)d_in[5];
  const float* W_post = (const float*)d_in[6];
  const float* b_post = (const float*)d_in[7];
  const float* W_lin  = (const float*)d_in[8];
  const float* b_lin  = (const float*)d_in[9];
  const float* gw     = (const float*)d_in[10];
  const float* gb     = (const float*)d_in[11];
  const float* alpha  = (const float*)d_in[12];
  float* y = (float*)d_out;

  float* wsf = (float*)d_ws;
  float* bc2   = wsf;                 // 128
  float* At    = wsf + 128;           // 2048*128 -> ends 262272
  float* agg   = wsf + 262272;        // 2048*512 -> ends 1310848
  float* outl  = wsf + 1310848;       // 2048*128 -> ends 1572992
  float* psum  = wsf + 1572992;       // 512*128 -> ends 1638528
  float* psq   = wsf + 1638528;       // 512*128 -> ends 1704064
  uint16_t* wct = (uint16_t*)(wsf + 1704064);  // 16384 bf16 = 8192 floats -> ends 1712256
  unsigned* bvl = (unsigned*)(wsf + 1712256);  // 2048*64 u32 (bf16 pairs) -> ends 1843328

  k_prep<<<1152, 128, 0, stream>>>(W_edge, b_edge, W_pre, b_pre, x, wct, bc2, At, bvl);
  k_edge<<<2048, 256, 0, stream>>>(edge, wct, bvl, At, bc2, agg);
  k_post<<<512, 256, 0, stream>>>(x, agg, W_post, b_post, W_lin, b_lin, outl, psum, psq);
  k_apply<<<256, 256, 0, stream>>>(psum, psq, outl, x, gw, gb, alpha, y);
}